// Round 13
// baseline (1683.738 us; speedup 1.0000x reference)
//
#include <hip/hip_runtime.h>

typedef unsigned short u16;
typedef unsigned int   u32;
typedef u16   u16x8 __attribute__((ext_vector_type(8)));
typedef __bf16 bf16x8 __attribute__((ext_vector_type(8)));
typedef float f32x4 __attribute__((ext_vector_type(4)));
typedef float f32x4v __attribute__((ext_vector_type(4)));

#define N_NODES 4096
#define N_EDGES 16384
#define N_EFEAT 16384
#define SEQ 8
#define DIM 512
#define NLAYER 2
#define NROWS_X (N_NODES*SEQ)     /* 32768 */
#define NROWS_E (N_EDGES*SEQ)     /* 131072 */

__device__ __forceinline__ float b2f(u16 u){ return __uint_as_float(((u32)u)<<16); }
__device__ __forceinline__ u16 f2b(float f){ u32 b=__float_as_uint(f); b += 0x7FFFu + ((b>>16)&1u); return (u16)(b>>16); }

__device__ __forceinline__ void gl16(const u16* g, u16* l) {
    __builtin_amdgcn_global_load_lds((const __attribute__((address_space(1))) void*)g,
                                     (__attribute__((address_space(3))) void*)l, 16, 0, 0);
}

// ---------------- weight transpose + norm-w fold: dst[N][K] = src[K][N] * fold[K] ----------------
__global__ void k_tf(const float* __restrict__ src, u16* __restrict__ dst,
                     const float* __restrict__ fold, int K, int N)
{
    int idx = blockIdx.x * 256 + threadIdx.x;
    if (idx >= K * N) return;
    int c = idx / N, j = idx - c * N;
    float v = src[idx];
    if (fold) v *= fold[c];
    dst[(size_t)j * K + c] = f2b(v);
}

// ---------------- layer-0 row prep: bf16 copy + per-row SUMSQ (wave per row) ----------------
__global__ void k_rowprep(const float* __restrict__ src, u16* __restrict__ dst,
                          float* __restrict__ ssout)
{
    int row  = blockIdx.x * 4 + (threadIdx.x >> 6);
    int lane = threadIdx.x & 63;
    const float* p = src + (size_t)row * DIM;
    f32x4v v0 = *(const f32x4v*)(p + lane * 8);
    f32x4v v1 = *(const f32x4v*)(p + lane * 8 + 4);
    float ss = v0[0]*v0[0]+v0[1]*v0[1]+v0[2]*v0[2]+v0[3]*v0[3]
             + v1[0]*v1[0]+v1[1]*v1[1]+v1[2]*v1[2]+v1[3]*v1[3];
    #pragma unroll
    for (int d = 1; d < 64; d <<= 1) ss += __shfl_xor(ss, d);
    if (lane == 0) ssout[row] = ss;
    u16x8 o;
    #pragma unroll
    for (int i = 0; i < 4; ++i) o[i] = f2b(v0[i]);
    #pragma unroll
    for (int i = 0; i < 4; ++i) o[4+i] = f2b(v1[i]);
    *(u16x8*)(dst + (size_t)row * DIM + lane * 8) = o;
}

// ---------------- feature dedup: ekv[e] = (RMS(feat) @ We)[emap[e]] (RMS commutes w/ gather) --
__global__ void k_mark(const int* __restrict__ emap, int* __restrict__ flag)
{
    int e = blockIdx.x * 256 + threadIdx.x;
    if (e < N_EDGES) flag[emap[e]] = 1;
}
// single block: exclusive scan of flag[16384] -> newid; ulist[newid[m]] = m; ucnt = total
__global__ void k_scanf(const int* __restrict__ flag, int* __restrict__ newid,
                        int* __restrict__ ulist, int* __restrict__ ucnt)
{
    __shared__ int part[256];
    int t = threadIdx.x;
    int base = t * 64;
    int loc[64]; int s = 0;
    #pragma unroll
    for (int i = 0; i < 64; ++i) { loc[i] = s; s += flag[base + i]; }
    part[t] = s; __syncthreads();
    for (int d = 1; d < 256; d <<= 1) {
        int v = (t >= d) ? part[t - d] : 0;
        __syncthreads();
        part[t] += v;
        __syncthreads();
    }
    int pre = (t == 0) ? 0 : part[t - 1];
    #pragma unroll
    for (int i = 0; i < 64; ++i) {
        int m = base + i;
        int id = pre + loc[i];
        newid[m] = id;
        if (flag[m]) ulist[id] = m;
    }
    if (t == 255) ucnt[0] = part[255];
}
__global__ void k_fidx(const int* __restrict__ emap, const int* __restrict__ newid,
                       int* __restrict__ fidx)
{
    int e = blockIdx.x * 256 + threadIdx.x;
    if (e < N_EDGES) fidx[e] = newid[emap[e]];
}
// compact-feature rows: SUMSQ + bf16 copy (wave per row); rows >= ucnt*8 skipped
__global__ void k_featprep(const float* __restrict__ hidden, const int* __restrict__ ulist,
                           const int* __restrict__ ucnt,
                           u16* __restrict__ fbf, float* __restrict__ ssout)
{
    int fr = blockIdx.x * 4 + (threadIdx.x >> 6);   // compact row = j*8+l
    if (fr >= ucnt[0] * SEQ) return;
    int lane = threadIdx.x & 63;
    int j = fr >> 3, l = fr & 7;
    const float* p = hidden + ((size_t)(N_NODES + ulist[j]) * SEQ + l) * DIM;
    f32x4v v0 = *(const f32x4v*)(p + lane * 8);
    f32x4v v1 = *(const f32x4v*)(p + lane * 8 + 4);
    float ss = v0[0]*v0[0]+v0[1]*v0[1]+v0[2]*v0[2]+v0[3]*v0[3]
             + v1[0]*v1[0]+v1[1]*v1[1]+v1[2]*v1[2]+v1[3]*v1[3];
    #pragma unroll
    for (int d = 1; d < 64; d <<= 1) ss += __shfl_xor(ss, d);
    if (lane == 0) ssout[fr] = ss;
    u16x8 o;
    #pragma unroll
    for (int i = 0; i < 4; ++i) o[i] = f2b(v0[i]);
    #pragma unroll
    for (int i = 0; i < 4; ++i) o[4+i] = f2b(v1[i]);
    *(u16x8*)(fbf + (size_t)fr * DIM + lane * 8) = o;
}

// ---------------- CSR build ----------------
__global__ void k_count(const int* __restrict__ dstA, int* __restrict__ cnt)
{
    int e = blockIdx.x * 256 + threadIdx.x;
    if (e < N_EDGES) atomicAdd(&cnt[dstA[e]], 1);
}
__global__ void k_scan(const int* __restrict__ cnt, int* __restrict__ off)
{
    __shared__ int part[256];
    int t = threadIdx.x;
    int base = t * 16;
    int loc[16]; int s = 0;
    #pragma unroll
    for (int i = 0; i < 16; ++i) { loc[i] = s; s += cnt[base + i]; }
    part[t] = s; __syncthreads();
    for (int d = 1; d < 256; d <<= 1) {
        int v = (t >= d) ? part[t - d] : 0;
        __syncthreads();
        part[t] += v;
        __syncthreads();
    }
    int pre = (t == 0) ? 0 : part[t - 1];
    #pragma unroll
    for (int i = 0; i < 16; ++i) off[base + i] = pre + loc[i];
    if (t == 255) off[N_NODES] = part[255];
}
__global__ void k_fill(const int* __restrict__ dstA, const int* __restrict__ off,
                       int* __restrict__ cur, int* __restrict__ elist)
{
    int e = blockIdx.x * 256 + threadIdx.x;
    if (e < N_EDGES) {
        int d = dstA[e];
        int pos = off[d] + atomicAdd(&cur[d], 1);
        elist[pos] = e;
    }
}

// ---------------- bf16 MFMA GEMM: r11 winning structure with ONE change: BK=32 -> 64.
// 2-phase __syncthreads loop, 128x128 tile, 4 waves of 64x64, gl_lds w=16 dbuf,
// interleaved-XCD mapping, fused epilogue. Halves barrier+vmcnt-drain events per block
// (16 -> 8 steps at K=512) while doubling MFMA per step. LDS 64 KiB -> 2 blocks/CU.
// Swizzle (same family, 0-conflict profile): row of 64 u16 = 8 chunks of 8 u16;
// physical chunk = logical chunk ^ (row & 7). Staging: linear LDS dest, source chunk
// pre-XOR'd; ds_read applies XOR with (m15 & 7).
__global__ __launch_bounds__(256, 2) void k_gemm(
    const u16* __restrict__ A, const u16* __restrict__ B,
    int M, int N, int K, int gx, const int* __restrict__ mrows,
    const float* __restrict__ ssin, const float* __restrict__ bias, int relu,
    const u16* __restrict__ resH, float* __restrict__ ssout,
    float* __restrict__ outF, u16* __restrict__ outH)
{
    __shared__ u16 ldsA[2][128 * 64];
    __shared__ u16 ldsB[2][128 * 64];
    int tid  = threadIdx.x;
    int lane = tid & 63, wid = tid >> 6;

    // interleaved XCD mapping (requires rowtiles % 8 == 0 — true for all shapes here)
    int xcd  = blockIdx.x & 7;
    int i    = blockIdx.x >> 3;
    int colt = i % gx;
    int rowt = (i / gx) * 8 + xcd;
    int row0 = rowt * 128, col0 = colt * 128;
    if (mrows && row0 >= mrows[0] * SEQ) return;   // uniform exit, before any barrier

    // staging: wave w covers rows [w*32, w*32+32) as 4 slots of 8 rows x 64 k (1 KB each).
    // lane -> row-in-slot rs = lane>>3, phys chunk pc = lane&7, source chunk = pc ^ rs.
    int rs = lane >> 3;
    int lc = (lane & 7) ^ rs;
    const u16* ga = A + (size_t)(row0 + wid * 32 + rs) * K + lc * 8;
    const u16* gb = B + (size_t)(col0 + wid * 32 + rs) * K + lc * 8;

    auto stage = [&](int buf, int kt) {
        int ko = kt * 64;
        #pragma unroll
        for (int s = 0; s < 4; ++s) {
            gl16(ga + (size_t)(s * 8) * K + ko, &ldsA[buf][(wid * 4 + s) * 512]);
            gl16(gb + (size_t)(s * 8) * K + ko, &ldsB[buf][(wid * 4 + s) * 512]);
        }
    };

    f32x4 acc[4][4];
    #pragma unroll
    for (int m = 0; m < 4; ++m)
        #pragma unroll
        for (int n = 0; n < 4; ++n) { f32x4 z = {0.f,0.f,0.f,0.f}; acc[m][n] = z; }

    int wr = wid >> 1, wc = wid & 1;
    int m15 = lane & 15, g = lane >> 4;
    int arow_l = wr * 64 + m15;   // + m*16 ; (row & 7) == (m15 & 7) since offsets are mult of 16
    int brow_l = wc * 64 + m15;
    int h7 = m15 & 7;

    int NT = K >> 6;
    stage(0, 0);
    int cur = 0;
    for (int kt = 0; kt < NT; ++kt) {
        __syncthreads();                        // drains vmcnt: buf[cur] ready, prev reads done
        if (kt + 1 < NT) stage(cur ^ 1, kt + 1);
        bf16x8 af[4][2], bfr[4][2];
        #pragma unroll
        for (int m = 0; m < 4; ++m)
            #pragma unroll
            for (int kk = 0; kk < 2; ++kk)
                af[m][kk] = *(const bf16x8*)&ldsA[cur][(arow_l + m * 16) * 64 + (((kk * 4 + g) ^ h7) << 3)];
        #pragma unroll
        for (int n = 0; n < 4; ++n)
            #pragma unroll
            for (int kk = 0; kk < 2; ++kk)
                bfr[n][kk] = *(const bf16x8*)&ldsB[cur][(brow_l + n * 16) * 64 + (((kk * 4 + g) ^ h7) << 3)];
        #pragma unroll
        for (int kk = 0; kk < 2; ++kk)
            #pragma unroll
            for (int m = 0; m < 4; ++m)
                #pragma unroll
                for (int n = 0; n < 4; ++n)
                    acc[m][n] = __builtin_amdgcn_mfma_f32_16x16x32_bf16(af[m][kk], bfr[n][kk], acc[m][n], 0, 0, 0);
        cur ^= 1;
    }

    // fused epilogue: row = row0 + wr*64 + m*16 + g*4 + j ; col = col0 + wc*64 + n*16 + m15
    #pragma unroll
    for (int m = 0; m < 4; ++m) {
        #pragma unroll
        for (int j = 0; j < 4; ++j) {
            int row = row0 + wr * 64 + m * 16 + g * 4 + j;
            float sc = 0.f;
            if (ssin) sc = rsqrtf(ssin[row] * (1.f / (float)DIM) + 1e-6f);
            float ssa = 0.f;
            #pragma unroll
            for (int n = 0; n < 4; ++n) {
                int col = col0 + wc * 64 + n * 16 + m15;
                float v = acc[m][n][j];
                if (ssin) v *= sc;
                if (bias) v += bias[col];
                if (relu) v = fmaxf(v, 0.f);
                if (resH) v += b2f(resH[(size_t)row * N + col]);
                if (outF) outF[(size_t)row * N + col] = v;
                if (outH) outH[(size_t)row * N + col] = f2b(v);
                ssa += v * v;
            }
            if (ssout) {
                ssa += __shfl_xor(ssa, 1);
                ssa += __shfl_xor(ssa, 2);
                ssa += __shfl_xor(ssa, 4);
                ssa += __shfl_xor(ssa, 8);
                if (m15 == 0) atomicAdd(&ssout[row], ssa);
            }
        }
    }
}

// ---------------- per-node attention: online segment softmax + aggregate (RoPE eliminated:
// both sides rotated by the same position l -> orthogonal rotation cancels in the dot).
// Edge features indexed via compact fidx[e] (dedup'd fkv table). ------
__global__ __launch_bounds__(256, 2) void k_attn(
    const u16* __restrict__ qkv, const u16* __restrict__ ekv,
    const int* __restrict__ srcA, const int* __restrict__ fidx,
    const int* __restrict__ off, const int* __restrict__ elist,
    u16* __restrict__ agg)
{
    int n = blockIdx.x;
    int t = threadIdx.x;
    int pair = t >> 2, sub = t & 3;
    int l = pair >> 3, hd = pair & 7;
    int doff = hd * 64 + sub * 16;

    size_t qrow = ((size_t)n * SEQ + l) * 1536;
    float qi[16];
    {
        u16x8 qa = *(const u16x8*)&qkv[qrow + doff];
        u16x8 qb = *(const u16x8*)&qkv[qrow + doff + 8];
        #pragma unroll
        for (int i = 0; i < 8; ++i) { qi[i] = b2f(qa[i]); qi[i + 8] = b2f(qb[i]); }
    }

    float mrun = -INFINITY, s = 0.f;
    float av[16];
    #pragma unroll
    for (int i = 0; i < 16; ++i) av[i] = 0.f;

    int e0 = off[n], e1 = off[n + 1];
    for (int ii = e0; ii < e1; ++ii) {
        int e = elist[ii];
        int es = srcA[e];
        size_t krow = ((size_t)es * SEQ + l) * 1536 + 512;
        size_t erow = ((size_t)fidx[e] * SEQ + l) * 1024;

        u16x8 ka = *(const u16x8*)&qkv[krow + doff];
        u16x8 kb = *(const u16x8*)&qkv[krow + doff + 8];
        u16x8 ea = *(const u16x8*)&ekv[erow + doff];
        u16x8 eb = *(const u16x8*)&ekv[erow + doff + 8];

        float dot = 0.f;
        #pragma unroll
        for (int i = 0; i < 8; ++i) {
            dot += qi[i]     * (b2f(ka[i]) + b2f(ea[i]));
            dot += qi[i + 8] * (b2f(kb[i]) + b2f(eb[i]));
        }
        dot += __shfl_xor(dot, 1);
        dot += __shfl_xor(dot, 2);
        float alpha = dot * 0.125f;     // 1/sqrt(64)

        float mn = fmaxf(mrun, alpha);
        float f = expf(mrun - mn);      // mrun=-inf -> 0
        float p = expf(alpha - mn);
        s = s * f + p;

        u16x8 va  = *(const u16x8*)&qkv[krow + 512 + doff];
        u16x8 vb  = *(const u16x8*)&qkv[krow + 512 + doff + 8];
        u16x8 eva = *(const u16x8*)&ekv[erow + 512 + doff];
        u16x8 evb = *(const u16x8*)&ekv[erow + 512 + doff + 8];
        #pragma unroll
        for (int i = 0; i < 8; ++i) {
            av[i]     = av[i]     * f + p * (b2f(va[i]) + b2f(eva[i]));
            av[i + 8] = av[i + 8] * f + p * (b2f(vb[i]) + b2f(evb[i]));
        }
        mrun = mn;
    }

    float inv = 1.f / (s + 1e-16f);
    size_t orow = ((size_t)n * SEQ + l) * DIM + doff;
    #pragma unroll
    for (int i = 0; i < 16; ++i) agg[orow + i] = f2b(av[i] * inv);
}

extern "C" void kernel_launch(void* const* d_in, const int* in_sizes, int n_in,
                              void* d_out, int out_size, void* d_ws, size_t ws_size,
                              hipStream_t stream)
{
    const float* hidden = (const float*)d_in[0];
    const int*   eidx   = (const int*)d_in[1];
    const int*   srcA   = eidx;              // edge_index[0]
    const int*   dstA   = eidx + N_EDGES;    // edge_index[1]
    const int*   emap   = (const int*)d_in[2];
    const float* W_qkv  = (const float*)d_in[4];
    const float* W_e    = (const float*)d_in[5];
    const float* W_o    = (const float*)d_in[6];
    const float* xw     = (const float*)d_in[7];
    const float* xew    = (const float*)d_in[8];
    const float* pw     = (const float*)d_in[9];
    const float* W1     = (const float*)d_in[10];
    const float* b1     = (const float*)d_in[11];
    const float* W2     = (const float*)d_in[12];
    const float* b2     = (const float*)d_in[13];

    char* w = (char*)d_ws;
    auto alloc = [&](size_t bytes) { char* p = w; w += (bytes + 255) & ~(size_t)255; return p; };
    u16*  WtQKV  = (u16*)alloc((size_t)NLAYER * 1536 * 512 * 2);
    u16*  WtE    = (u16*)alloc((size_t)NLAYER * 1024 * 512 * 2);
    u16*  WtO    = (u16*)alloc((size_t)NLAYER * 512 * 512 * 2);
    u16*  Wt1    = (u16*)alloc((size_t)NLAYER * 1024 * 512 * 2);
    u16*  Wt2    = (u16*)alloc((size_t)NLAYER * 512 * 1024 * 2);
    float* ssx0  = (float*)alloc((size_t)NROWS_X * 4);
    float* ssx1  = (float*)alloc((size_t)NROWS_X * 4);
    float* ssp0  = (float*)alloc((size_t)NROWS_X * 4);
    float* ssp1  = (float*)alloc((size_t)NROWS_X * 4);
    float* s_f   = (float*)alloc((size_t)NROWS_E * 4);
    int*  cnt    = (int*)alloc((N_NODES + 1) * 4);
    int*  off    = (int*)alloc((N_NODES + 1) * 4);
    int*  cur    = (int*)alloc(N_NODES * 4);
    int*  elist  = (int*)alloc(N_EDGES * 4);
    int*  flag   = (int*)alloc(N_EFEAT * 4);
    int*  newid  = (int*)alloc(N_EFEAT * 4);
    int*  ulist  = (int*)alloc(N_EFEAT * 4);
    int*  fidx   = (int*)alloc(N_EDGES * 4);
    int*  ucnt   = (int*)alloc(256);
    u16*  hb     = (u16*)alloc((size_t)NROWS_X * DIM * 2);
    u16*  ob     = (u16*)alloc((size_t)NROWS_X * DIM * 2);
    u16*  fbf    = (u16*)alloc((size_t)NROWS_E * DIM * 2);
    u16*  qkv    = (u16*)alloc((size_t)NROWS_X * 1536 * 2);
    u16*  aggB   = (u16*)alloc((size_t)NROWS_X * DIM * 2);
    u16*  ffmid  = (u16*)alloc((size_t)NROWS_X * 1024 * 2);
    // ekv scratch lives in d_out's edge region (exact size match: 131072*1024*2B = 16384*4096*4B)
    u16*  ekv    = (u16*)((float*)d_out + (size_t)NROWS_X * DIM);
    float* ssx[2] = { ssx0, ssx1 };
    float* ssp[2] = { ssp0, ssp1 };

    // ---- one-time prep ----
    for (int l = 0; l < NLAYER; ++l) {
        k_tf<<<(512*1536 + 255)/256, 256, 0, stream>>>(W_qkv + (size_t)l*512*1536, WtQKV + (size_t)l*1536*512, xw  + l*512, 512, 1536);
        k_tf<<<(512*1024 + 255)/256, 256, 0, stream>>>(W_e   + (size_t)l*512*1024, WtE   + (size_t)l*1024*512, xew + l*512, 512, 1024);
        k_tf<<<(512*512  + 255)/256, 256, 0, stream>>>(W_o   + (size_t)l*512*512,  WtO   + (size_t)l*512*512,  nullptr,    512, 512);
        k_tf<<<(512*1024 + 255)/256, 256, 0, stream>>>(W1    + (size_t)l*512*1024, Wt1   + (size_t)l*1024*512, pw  + l*512, 512, 1024);
        k_tf<<<(1024*512 + 255)/256, 256, 0, stream>>>(W2    + (size_t)l*1024*512, Wt2   + (size_t)l*512*1024, nullptr,    1024, 512);
    }
    // zero atomic-sumsq accumulators (re-zeroed every call; graph-replay safe)
    hipMemsetAsync(ssx1, 0, NROWS_X * 4, stream);
    hipMemsetAsync(ssp0, 0, NROWS_X * 4, stream);
    hipMemsetAsync(ssp1, 0, NROWS_X * 4, stream);
    // dedup + compact-feature prep
    hipMemsetAsync(flag, 0, N_EFEAT * 4, stream);
    k_mark<<<N_EDGES/256, 256, 0, stream>>>(emap, flag);
    k_scanf<<<1, 256, 0, stream>>>(flag, newid, ulist, ucnt);
    k_fidx<<<N_EDGES/256, 256, 0, stream>>>(emap, newid, fidx);
    k_featprep<<<NROWS_E/4, 256, 0, stream>>>(hidden, ulist, ucnt, fbf, s_f);
    // CSR by dst
    hipMemsetAsync(cnt, 0, (N_NODES + 1) * 4, stream);
    hipMemsetAsync(cur, 0, N_NODES * 4, stream);
    k_count<<<N_EDGES/256, 256, 0, stream>>>(dstA, cnt);
    k_scan<<<1, 256, 0, stream>>>(cnt, off);
    k_fill<<<N_EDGES/256, 256, 0, stream>>>(dstA, off, cur, elist);
    // layer-0 node prep: bf16 copy + sumsq
    k_rowprep<<<NROWS_X/4, 256, 0, stream>>>(hidden, hb, ssx0);

    // ---- layers (all state bf16; RMS scales from fused sumsq) ----
    for (int l = 0; l < NLAYER; ++l) {
        int last = (l == NLAYER - 1);
        // qkv = rms(h)@Wqkv  (rowscale from ssx[l])
        k_gemm<<<(NROWS_X/128)*(1536/128), 256, 0, stream>>>(hb, WtQKV + (size_t)l*1536*512,
            NROWS_X, 1536, 512, 1536/128, nullptr,
            ssx[l], nullptr, 0, nullptr, nullptr, nullptr, qkv);
        // ekv = rms(feat)@We  (dedup'd rows; rowscale from s_f)
        k_gemm<<<(NROWS_E/128)*(1024/128), 256, 0, stream>>>(fbf, WtE + (size_t)l*1024*512,
            NROWS_E, 1024, 512, 1024/128, ucnt,
            s_f, nullptr, 0, nullptr, nullptr, nullptr, ekv);
        k_attn<<<N_NODES, 256, 0, stream>>>(qkv, ekv, srcA, fidx, off, elist, aggB);
        // out = h + agg@Wo   -> ob (bf16) + sumsq(out) -> ssp[l]
        k_gemm<<<(NROWS_X/128)*(512/128), 256, 0, stream>>>(aggB, WtO + (size_t)l*512*512,
            NROWS_X, 512, 512, 512/128, nullptr,
            nullptr, nullptr, 0, hb, ssp[l], nullptr, ob);
        // ffmid = relu(rms(out)@W1 + b1)   (rowscale from ssp[l])
        k_gemm<<<(NROWS_X/128)*(1024/128), 256, 0, stream>>>(ob, Wt1 + (size_t)l*1024*512,
            NROWS_X, 1024, 512, 1024/128, nullptr,
            ssp[l], b1 + l*1024, 1, nullptr, nullptr, nullptr, ffmid);
        // h' = out + ffmid@W2 + b2  -> hb (bf16) + sumsq -> ssx[l+1]; last: fp32 d_out
        k_gemm<<<(NROWS_X/128)*(512/128), 256, 0, stream>>>(ffmid, Wt2 + (size_t)l*512*1024,
            NROWS_X, 512, 1024, 512/128, nullptr,
            nullptr, b2 + l*512, 0, ob,
            last ? nullptr : ssx[1],
            last ? (float*)d_out : nullptr,
            last ? nullptr : hb);
    }

    // ---- edge-region copy (also overwrites ekv scratch; node region written by last FF2) ----
    hipMemcpyAsync((float*)d_out + (size_t)NROWS_X * DIM, hidden + (size_t)NROWS_X * DIM,
                   (size_t)N_EDGES * SEQ * DIM * 4, hipMemcpyDeviceToDevice, stream);
}

// Round 14
// 1481.770 us; speedup vs baseline: 1.1363x; 1.1363x over previous
//
#include <hip/hip_runtime.h>

typedef unsigned short u16;
typedef unsigned int   u32;
typedef u16   u16x8 __attribute__((ext_vector_type(8)));
typedef __bf16 bf16x8 __attribute__((ext_vector_type(8)));
typedef float f32x4 __attribute__((ext_vector_type(4)));
typedef float f32x4v __attribute__((ext_vector_type(4)));

#define N_NODES 4096
#define N_EDGES 16384
#define N_EFEAT 16384
#define SEQ 8
#define DIM 512
#define NLAYER 2
#define NROWS_X (N_NODES*SEQ)     /* 32768 */
#define NROWS_E (N_EDGES*SEQ)     /* 131072 */

__device__ __forceinline__ float b2f(u16 u){ return __uint_as_float(((u32)u)<<16); }
__device__ __forceinline__ u16 f2b(float f){ u32 b=__float_as_uint(f); b += 0x7FFFu + ((b>>16)&1u); return (u16)(b>>16); }

__device__ __forceinline__ void gl16(const u16* g, u16* l) {
    __builtin_amdgcn_global_load_lds((const __attribute__((address_space(1))) void*)g,
                                     (__attribute__((address_space(3))) void*)l, 16, 0, 0);
}

// ---------------- weight transpose + norm-w fold: dst[N][K] = src[K][N] * fold[K] ----------------
__global__ void k_tf(const float* __restrict__ src, u16* __restrict__ dst,
                     const float* __restrict__ fold, int K, int N)
{
    int idx = blockIdx.x * 256 + threadIdx.x;
    if (idx >= K * N) return;
    int c = idx / N, j = idx - c * N;
    float v = src[idx];
    if (fold) v *= fold[c];
    dst[(size_t)j * K + c] = f2b(v);
}

// ---------------- layer-0 row prep: bf16 copy + per-row SUMSQ (wave per row) ----------------
__global__ void k_rowprep(const float* __restrict__ src, u16* __restrict__ dst,
                          float* __restrict__ ssout)
{
    int row  = blockIdx.x * 4 + (threadIdx.x >> 6);
    int lane = threadIdx.x & 63;
    const float* p = src + (size_t)row * DIM;
    f32x4v v0 = *(const f32x4v*)(p + lane * 8);
    f32x4v v1 = *(const f32x4v*)(p + lane * 8 + 4);
    float ss = v0[0]*v0[0]+v0[1]*v0[1]+v0[2]*v0[2]+v0[3]*v0[3]
             + v1[0]*v1[0]+v1[1]*v1[1]+v1[2]*v1[2]+v1[3]*v1[3];
    #pragma unroll
    for (int d = 1; d < 64; d <<= 1) ss += __shfl_xor(ss, d);
    if (lane == 0) ssout[row] = ss;
    u16x8 o;
    #pragma unroll
    for (int i = 0; i < 4; ++i) o[i] = f2b(v0[i]);
    #pragma unroll
    for (int i = 0; i < 4; ++i) o[4+i] = f2b(v1[i]);
    *(u16x8*)(dst + (size_t)row * DIM + lane * 8) = o;
}

// ---------------- feature dedup: ekv[e] = (RMS(feat) @ We)[emap[e]] (RMS commutes w/ gather) --
__global__ void k_mark(const int* __restrict__ emap, int* __restrict__ flag)
{
    int e = blockIdx.x * 256 + threadIdx.x;
    if (e < N_EDGES) flag[emap[e]] = 1;
}
// single block: exclusive scan of flag[16384] -> newid; ulist[newid[m]] = m; ucnt = total
__global__ void k_scanf(const int* __restrict__ flag, int* __restrict__ newid,
                        int* __restrict__ ulist, int* __restrict__ ucnt)
{
    __shared__ int part[256];
    int t = threadIdx.x;
    int base = t * 64;
    int loc[64]; int s = 0;
    #pragma unroll
    for (int i = 0; i < 64; ++i) { loc[i] = s; s += flag[base + i]; }
    part[t] = s; __syncthreads();
    for (int d = 1; d < 256; d <<= 1) {
        int v = (t >= d) ? part[t - d] : 0;
        __syncthreads();
        part[t] += v;
        __syncthreads();
    }
    int pre = (t == 0) ? 0 : part[t - 1];
    #pragma unroll
    for (int i = 0; i < 64; ++i) {
        int m = base + i;
        int id = pre + loc[i];
        newid[m] = id;
        if (flag[m]) ulist[id] = m;
    }
    if (t == 255) ucnt[0] = part[255];
}
__global__ void k_fidx(const int* __restrict__ emap, const int* __restrict__ newid,
                       int* __restrict__ fidx)
{
    int e = blockIdx.x * 256 + threadIdx.x;
    if (e < N_EDGES) fidx[e] = newid[emap[e]];
}
// compact-feature rows: SUMSQ + bf16 copy (wave per row); rows >= ucnt*8 skipped
__global__ void k_featprep(const float* __restrict__ hidden, const int* __restrict__ ulist,
                           const int* __restrict__ ucnt,
                           u16* __restrict__ fbf, float* __restrict__ ssout)
{
    int fr = blockIdx.x * 4 + (threadIdx.x >> 6);   // compact row = j*8+l
    if (fr >= ucnt[0] * SEQ) return;
    int lane = threadIdx.x & 63;
    int j = fr >> 3, l = fr & 7;
    const float* p = hidden + ((size_t)(N_NODES + ulist[j]) * SEQ + l) * DIM;
    f32x4v v0 = *(const f32x4v*)(p + lane * 8);
    f32x4v v1 = *(const f32x4v*)(p + lane * 8 + 4);
    float ss = v0[0]*v0[0]+v0[1]*v0[1]+v0[2]*v0[2]+v0[3]*v0[3]
             + v1[0]*v1[0]+v1[1]*v1[1]+v1[2]*v1[2]+v1[3]*v1[3];
    #pragma unroll
    for (int d = 1; d < 64; d <<= 1) ss += __shfl_xor(ss, d);
    if (lane == 0) ssout[fr] = ss;
    u16x8 o;
    #pragma unroll
    for (int i = 0; i < 4; ++i) o[i] = f2b(v0[i]);
    #pragma unroll
    for (int i = 0; i < 4; ++i) o[4+i] = f2b(v1[i]);
    *(u16x8*)(fbf + (size_t)fr * DIM + lane * 8) = o;
}

// ---------------- CSR build ----------------
__global__ void k_count(const int* __restrict__ dstA, int* __restrict__ cnt)
{
    int e = blockIdx.x * 256 + threadIdx.x;
    if (e < N_EDGES) atomicAdd(&cnt[dstA[e]], 1);
}
__global__ void k_scan(const int* __restrict__ cnt, int* __restrict__ off)
{
    __shared__ int part[256];
    int t = threadIdx.x;
    int base = t * 16;
    int loc[16]; int s = 0;
    #pragma unroll
    for (int i = 0; i < 16; ++i) { loc[i] = s; s += cnt[base + i]; }
    part[t] = s; __syncthreads();
    for (int d = 1; d < 256; d <<= 1) {
        int v = (t >= d) ? part[t - d] : 0;
        __syncthreads();
        part[t] += v;
        __syncthreads();
    }
    int pre = (t == 0) ? 0 : part[t - 1];
    #pragma unroll
    for (int i = 0; i < 16; ++i) off[base + i] = pre + loc[i];
    if (t == 255) off[N_NODES] = part[255];
}
__global__ void k_fill(const int* __restrict__ dstA, const int* __restrict__ off,
                       int* __restrict__ cur, int* __restrict__ elist)
{
    int e = blockIdx.x * 256 + threadIdx.x;
    if (e < N_EDGES) {
        int d = dstA[e];
        int pos = off[d] + atomicAdd(&cur[d], 1);
        elist[pos] = e;
    }
}

// ---------------- bf16 MFMA GEMM body: r11/r12's proven config (2-phase __syncthreads,
// 128x128 tile, BK=32, 4 waves of 64x64, gl_lds w=16 dbuf, 32 KiB LDS, interleaved-XCD
// mapping, 0-conflict swizzle, fused epilogue). Shared by k_gemm (single) and
// k_gemm2 (two independent GEMMs in one dispatch — fills the first GEMM's drain tail
// with the second GEMM's blocks; same-stream kernels can never overlap otherwise).
__device__ __forceinline__ void gemm_body(
    int bid, u16* ldsA0, u16* ldsA1, u16* ldsB0, u16* ldsB1,
    const u16* __restrict__ A, const u16* __restrict__ B,
    int N, int K, int gx, const int* __restrict__ mrows,
    const float* __restrict__ ssin, const float* __restrict__ bias, int relu,
    const u16* __restrict__ resH, float* __restrict__ ssout,
    float* __restrict__ outF, u16* __restrict__ outH)
{
    u16* ldsA[2] = { ldsA0, ldsA1 };
    u16* ldsB[2] = { ldsB0, ldsB1 };
    int tid  = threadIdx.x;
    int lane = tid & 63, wid = tid >> 6;

    // interleaved XCD mapping (requires rowtiles % 8 == 0 — true for all shapes here)
    int xcd  = bid & 7;
    int i    = bid >> 3;
    int colt = i % gx;
    int rowt = (i / gx) * 8 + xcd;
    int row0 = rowt * 128, col0 = colt * 128;
    if (mrows && row0 >= mrows[0] * SEQ) return;   // uniform exit, before any barrier

    // staging: wave w covers rows [w*32, w*32+32) in two 16-row slots; inverse-swizzled source
    int r0 = wid * 32 + (lane >> 2);
    int r1 = r0 + 16;
    int ce0 = ((lane & 3) * 8) ^ (((r0 >> 1) & 3) << 3);
    int ce1 = ((lane & 3) * 8) ^ (((r1 >> 1) & 3) << 3);
    const u16* ga0 = A + (size_t)(row0 + r0) * K + ce0;
    const u16* ga1 = A + (size_t)(row0 + r1) * K + ce1;
    const u16* gb0 = B + (size_t)(col0 + r0) * K + ce0;
    const u16* gb1 = B + (size_t)(col0 + r1) * K + ce1;

    auto stage = [&](int buf, int kt) {
        int ko = kt * 32;
        gl16(ga0 + ko, &ldsA[buf][wid * 1024]);
        gl16(ga1 + ko, &ldsA[buf][wid * 1024 + 512]);
        gl16(gb0 + ko, &ldsB[buf][wid * 1024]);
        gl16(gb1 + ko, &ldsB[buf][wid * 1024 + 512]);
    };

    f32x4 acc[4][4];
    #pragma unroll
    for (int m = 0; m < 4; ++m)
        #pragma unroll
        for (int n = 0; n < 4; ++n) { f32x4 z = {0.f,0.f,0.f,0.f}; acc[m][n] = z; }

    int wr = wid >> 1, wc = wid & 1;
    int m15 = lane & 15, g = lane >> 4;
    int arow_l = wr * 64 + m15;
    int brow_l = wc * 64 + m15;
    // swizzled k-offset (u16): row bits 1-2 come from m15 regardless of +m*16
    int ksw = (g * 8) ^ (((m15 >> 1) & 3) << 3);

    int NT = K / 32;
    stage(0, 0);
    int cur = 0;
    for (int kt = 0; kt < NT; ++kt) {
        __syncthreads();                        // drains vmcnt: buf[cur] ready, prev reads done
        if (kt + 1 < NT) stage(cur ^ 1, kt + 1);
        bf16x8 af[4], bfr[4];
        #pragma unroll
        for (int m = 0; m < 4; ++m)
            af[m] = *(const bf16x8*)&ldsA[cur][(arow_l + m * 16) * 32 + ksw];
        #pragma unroll
        for (int n = 0; n < 4; ++n)
            bfr[n] = *(const bf16x8*)&ldsB[cur][(brow_l + n * 16) * 32 + ksw];
        #pragma unroll
        for (int m = 0; m < 4; ++m)
            #pragma unroll
            for (int n = 0; n < 4; ++n)
                acc[m][n] = __builtin_amdgcn_mfma_f32_16x16x32_bf16(af[m], bfr[n], acc[m][n], 0, 0, 0);
        cur ^= 1;
    }

    // fused epilogue: row = row0 + wr*64 + m*16 + g*4 + j ; col = col0 + wc*64 + n*16 + m15
    #pragma unroll
    for (int m = 0; m < 4; ++m) {
        #pragma unroll
        for (int j = 0; j < 4; ++j) {
            int row = row0 + wr * 64 + m * 16 + g * 4 + j;
            float sc = 0.f;
            if (ssin) sc = rsqrtf(ssin[row] * (1.f / (float)DIM) + 1e-6f);
            float ssa = 0.f;
            #pragma unroll
            for (int n = 0; n < 4; ++n) {
                int col = col0 + wc * 64 + n * 16 + m15;
                float v = acc[m][n][j];
                if (ssin) v *= sc;
                if (bias) v += bias[col];
                if (relu) v = fmaxf(v, 0.f);
                if (resH) v += b2f(resH[(size_t)row * N + col]);
                if (outF) outF[(size_t)row * N + col] = v;
                if (outH) outH[(size_t)row * N + col] = f2b(v);
                ssa += v * v;
            }
            if (ssout) {
                ssa += __shfl_xor(ssa, 1);
                ssa += __shfl_xor(ssa, 2);
                ssa += __shfl_xor(ssa, 4);
                ssa += __shfl_xor(ssa, 8);
                if (m15 == 0) atomicAdd(&ssout[row], ssa);
            }
        }
    }
}

__global__ __launch_bounds__(256, 2) void k_gemm(
    const u16* __restrict__ A, const u16* __restrict__ B,
    int M, int N, int K, int gx, const int* __restrict__ mrows,
    const float* __restrict__ ssin, const float* __restrict__ bias, int relu,
    const u16* __restrict__ resH, float* __restrict__ ssout,
    float* __restrict__ outF, u16* __restrict__ outH)
{
    __shared__ u16 ldsA[2][128 * 32];
    __shared__ u16 ldsB[2][128 * 32];
    gemm_body(blockIdx.x, ldsA[0], ldsA[1], ldsB[0], ldsB[1],
              A, B, N, K, gx, mrows, ssin, bias, relu, resH, ssout, outF, outH);
}

// two independent GEMMs, one dispatch (blocks < nb0 -> set 0; else set 1). nb0 % 8 == 0
// keeps the per-half XCD mapping aligned.
__global__ __launch_bounds__(256, 2) void k_gemm2(
    int nb0,
    const u16* __restrict__ A0, const u16* __restrict__ B0,
    int N0, int K0, int gx0, const int* __restrict__ mrows0,
    const float* __restrict__ ssin0, const float* __restrict__ bias0, int relu0,
    const u16* __restrict__ resH0, float* __restrict__ ssout0,
    float* __restrict__ outF0, u16* __restrict__ outH0,
    const u16* __restrict__ A1, const u16* __restrict__ B1,
    int N1, int K1, int gx1, const int* __restrict__ mrows1,
    const float* __restrict__ ssin1, const float* __restrict__ bias1, int relu1,
    const u16* __restrict__ resH1, float* __restrict__ ssout1,
    float* __restrict__ outF1, u16* __restrict__ outH1)
{
    __shared__ u16 ldsA[2][128 * 32];
    __shared__ u16 ldsB[2][128 * 32];
    if ((int)blockIdx.x < nb0)
        gemm_body(blockIdx.x, ldsA[0], ldsA[1], ldsB[0], ldsB[1],
                  A0, B0, N0, K0, gx0, mrows0, ssin0, bias0, relu0, resH0, ssout0, outF0, outH0);
    else
        gemm_body(blockIdx.x - nb0, ldsA[0], ldsA[1], ldsB[0], ldsB[1],
                  A1, B1, N1, K1, gx1, mrows1, ssin1, bias1, relu1, resH1, ssout1, outF1, outH1);
}

// ---------------- per-node attention: online segment softmax + aggregate (RoPE eliminated:
// both sides rotated by the same position l -> orthogonal rotation cancels in the dot).
// Edge features indexed via compact fidx[e] (dedup'd fkv table). ------
__global__ __launch_bounds__(256, 2) void k_attn(
    const u16* __restrict__ qkv, const u16* __restrict__ ekv,
    const int* __restrict__ srcA, const int* __restrict__ fidx,
    const int* __restrict__ off, const int* __restrict__ elist,
    u16* __restrict__ agg)
{
    int n = blockIdx.x;
    int t = threadIdx.x;
    int pair = t >> 2, sub = t & 3;
    int l = pair >> 3, hd = pair & 7;
    int doff = hd * 64 + sub * 16;

    size_t qrow = ((size_t)n * SEQ + l) * 1536;
    float qi[16];
    {
        u16x8 qa = *(const u16x8*)&qkv[qrow + doff];
        u16x8 qb = *(const u16x8*)&qkv[qrow + doff + 8];
        #pragma unroll
        for (int i = 0; i < 8; ++i) { qi[i] = b2f(qa[i]); qi[i + 8] = b2f(qb[i]); }
    }

    float mrun = -INFINITY, s = 0.f;
    float av[16];
    #pragma unroll
    for (int i = 0; i < 16; ++i) av[i] = 0.f;

    int e0 = off[n], e1 = off[n + 1];
    for (int ii = e0; ii < e1; ++ii) {
        int e = elist[ii];
        int es = srcA[e];
        size_t krow = ((size_t)es * SEQ + l) * 1536 + 512;
        size_t erow = ((size_t)fidx[e] * SEQ + l) * 1024;

        u16x8 ka = *(const u16x8*)&qkv[krow + doff];
        u16x8 kb = *(const u16x8*)&qkv[krow + doff + 8];
        u16x8 ea = *(const u16x8*)&ekv[erow + doff];
        u16x8 eb = *(const u16x8*)&ekv[erow + doff + 8];

        float dot = 0.f;
        #pragma unroll
        for (int i = 0; i < 8; ++i) {
            dot += qi[i]     * (b2f(ka[i]) + b2f(ea[i]));
            dot += qi[i + 8] * (b2f(kb[i]) + b2f(eb[i]));
        }
        dot += __shfl_xor(dot, 1);
        dot += __shfl_xor(dot, 2);
        float alpha = dot * 0.125f;     // 1/sqrt(64)

        float mn = fmaxf(mrun, alpha);
        float f = expf(mrun - mn);      // mrun=-inf -> 0
        float p = expf(alpha - mn);
        s = s * f + p;

        u16x8 va  = *(const u16x8*)&qkv[krow + 512 + doff];
        u16x8 vb  = *(const u16x8*)&qkv[krow + 512 + doff + 8];
        u16x8 eva = *(const u16x8*)&ekv[erow + 512 + doff];
        u16x8 evb = *(const u16x8*)&ekv[erow + 512 + doff + 8];
        #pragma unroll
        for (int i = 0; i < 8; ++i) {
            av[i]     = av[i]     * f + p * (b2f(va[i]) + b2f(eva[i]));
            av[i + 8] = av[i + 8] * f + p * (b2f(vb[i]) + b2f(evb[i]));
        }
        mrun = mn;
    }

    float inv = 1.f / (s + 1e-16f);
    size_t orow = ((size_t)n * SEQ + l) * DIM + doff;
    #pragma unroll
    for (int i = 0; i < 16; ++i) agg[orow + i] = f2b(av[i] * inv);
}

extern "C" void kernel_launch(void* const* d_in, const int* in_sizes, int n_in,
                              void* d_out, int out_size, void* d_ws, size_t ws_size,
                              hipStream_t stream)
{
    const float* hidden = (const float*)d_in[0];
    const int*   eidx   = (const int*)d_in[1];
    const int*   srcA   = eidx;              // edge_index[0]
    const int*   dstA   = eidx + N_EDGES;    // edge_index[1]
    const int*   emap   = (const int*)d_in[2];
    const float* W_qkv  = (const float*)d_in[4];
    const float* W_e    = (const float*)d_in[5];
    const float* W_o    = (const float*)d_in[6];
    const float* xw     = (const float*)d_in[7];
    const float* xew    = (const float*)d_in[8];
    const float* pw     = (const float*)d_in[9];
    const float* W1     = (const float*)d_in[10];
    const float* b1     = (const float*)d_in[11];
    const float* W2     = (const float*)d_in[12];
    const float* b2     = (const float*)d_in[13];

    char* w = (char*)d_ws;
    auto alloc = [&](size_t bytes) { char* p = w; w += (bytes + 255) & ~(size_t)255; return p; };
    u16*  WtQKV  = (u16*)alloc((size_t)NLAYER * 1536 * 512 * 2);
    u16*  WtE    = (u16*)alloc((size_t)NLAYER * 1024 * 512 * 2);
    u16*  WtO    = (u16*)alloc((size_t)NLAYER * 512 * 512 * 2);
    u16*  Wt1    = (u16*)alloc((size_t)NLAYER * 1024 * 512 * 2);
    u16*  Wt2    = (u16*)alloc((size_t)NLAYER * 512 * 1024 * 2);
    float* ssx0  = (float*)alloc((size_t)NROWS_X * 4);
    float* ssx1  = (float*)alloc((size_t)NROWS_X * 4);
    float* ssp0  = (float*)alloc((size_t)NROWS_X * 4);
    float* ssp1  = (float*)alloc((size_t)NROWS_X * 4);
    float* s_f   = (float*)alloc((size_t)NROWS_E * 4);
    int*  cnt    = (int*)alloc((N_NODES + 1) * 4);
    int*  off    = (int*)alloc((N_NODES + 1) * 4);
    int*  cur    = (int*)alloc(N_NODES * 4);
    int*  elist  = (int*)alloc(N_EDGES * 4);
    int*  flag   = (int*)alloc(N_EFEAT * 4);
    int*  newid  = (int*)alloc(N_EFEAT * 4);
    int*  ulist  = (int*)alloc(N_EFEAT * 4);
    int*  fidx   = (int*)alloc(N_EDGES * 4);
    int*  ucnt   = (int*)alloc(256);
    u16*  hb     = (u16*)alloc((size_t)NROWS_X * DIM * 2);
    u16*  ob     = (u16*)alloc((size_t)NROWS_X * DIM * 2);
    u16*  fbf    = (u16*)alloc((size_t)NROWS_E * DIM * 2);
    u16*  qkv    = (u16*)alloc((size_t)NROWS_X * 1536 * 2);
    u16*  aggB   = (u16*)alloc((size_t)NROWS_X * DIM * 2);
    u16*  ffmid  = (u16*)alloc((size_t)NROWS_X * 1024 * 2);
    // ekv scratch lives in d_out's edge region (exact size match: 131072*1024*2B = 16384*4096*4B)
    u16*  ekv    = (u16*)((float*)d_out + (size_t)NROWS_X * DIM);
    float* ssx[2] = { ssx0, ssx1 };
    float* ssp[2] = { ssp0, ssp1 };

    // ---- one-time prep ----
    for (int l = 0; l < NLAYER; ++l) {
        k_tf<<<(512*1536 + 255)/256, 256, 0, stream>>>(W_qkv + (size_t)l*512*1536, WtQKV + (size_t)l*1536*512, xw  + l*512, 512, 1536);
        k_tf<<<(512*1024 + 255)/256, 256, 0, stream>>>(W_e   + (size_t)l*512*1024, WtE   + (size_t)l*1024*512, xew + l*512, 512, 1024);
        k_tf<<<(512*512  + 255)/256, 256, 0, stream>>>(W_o   + (size_t)l*512*512,  WtO   + (size_t)l*512*512,  nullptr,    512, 512);
        k_tf<<<(512*1024 + 255)/256, 256, 0, stream>>>(W1    + (size_t)l*512*1024, Wt1   + (size_t)l*1024*512, pw  + l*512, 512, 1024);
        k_tf<<<(1024*512 + 255)/256, 256, 0, stream>>>(W2    + (size_t)l*1024*512, Wt2   + (size_t)l*512*1024, nullptr,    1024, 512);
    }
    // zero atomic-sumsq accumulators (re-zeroed every call; graph-replay safe)
    hipMemsetAsync(ssx1, 0, NROWS_X * 4, stream);
    hipMemsetAsync(ssp0, 0, NROWS_X * 4, stream);
    hipMemsetAsync(ssp1, 0, NROWS_X * 4, stream);
    // dedup + compact-feature prep
    hipMemsetAsync(flag, 0, N_EFEAT * 4, stream);
    k_mark<<<N_EDGES/256, 256, 0, stream>>>(emap, flag);
    k_scanf<<<1, 256, 0, stream>>>(flag, newid, ulist, ucnt);
    k_fidx<<<N_EDGES/256, 256, 0, stream>>>(emap, newid, fidx);
    k_featprep<<<NROWS_E/4, 256, 0, stream>>>(hidden, ulist, ucnt, fbf, s_f);
    // CSR by dst
    hipMemsetAsync(cnt, 0, (N_NODES + 1) * 4, stream);
    hipMemsetAsync(cur, 0, N_NODES * 4, stream);
    k_count<<<N_EDGES/256, 256, 0, stream>>>(dstA, cnt);
    k_scan<<<1, 256, 0, stream>>>(cnt, off);
    k_fill<<<N_EDGES/256, 256, 0, stream>>>(dstA, off, cur, elist);
    // layer-0 node prep: bf16 copy + sumsq
    k_rowprep<<<NROWS_X/4, 256, 0, stream>>>(hidden, hb, ssx0);

    const int nbQ = (NROWS_X/128)*(1536/128);   // 3072 (div by 8)
    const int nbE = (NROWS_E/128)*(1024/128);   // 8192

    // ---- layers (all state bf16; RMS scales from fused sumsq) ----
    for (int l = 0; l < NLAYER; ++l) {
        int last = (l == NLAYER - 1);
        // qkv = rms(h)@Wqkv  +  ekv = rms(feat)@We (dedup'd) — ONE dispatch, tail-filled
        k_gemm2<<<nbQ + nbE, 256, 0, stream>>>(nbQ,
            hb, WtQKV + (size_t)l*1536*512, 1536, 512, 1536/128, nullptr,
            ssx[l], nullptr, 0, nullptr, nullptr, nullptr, qkv,
            fbf, WtE + (size_t)l*1024*512, 1024, 512, 1024/128, ucnt,
            s_f, nullptr, 0, nullptr, nullptr, nullptr, ekv);
        k_attn<<<N_NODES, 256, 0, stream>>>(qkv, ekv, srcA, fidx, off, elist, aggB);
        // out = h + agg@Wo   -> ob (bf16) + sumsq(out) -> ssp[l]
        k_gemm<<<(NROWS_X/128)*(512/128), 256, 0, stream>>>(aggB, WtO + (size_t)l*512*512,
            NROWS_X, 512, 512, 512/128, nullptr,
            nullptr, nullptr, 0, hb, ssp[l], nullptr, ob);
        // ffmid = relu(rms(out)@W1 + b1)   (rowscale from ssp[l])
        k_gemm<<<(NROWS_X/128)*(1024/128), 256, 0, stream>>>(ob, Wt1 + (size_t)l*1024*512,
            NROWS_X, 1024, 512, 1024/128, nullptr,
            ssp[l], b1 + l*1024, 1, nullptr, nullptr, nullptr, ffmid);
        // h' = out + ffmid@W2 + b2  -> hb (bf16) + sumsq -> ssx[l+1]; last: fp32 d_out
        k_gemm<<<(NROWS_X/128)*(512/128), 256, 0, stream>>>(ffmid, Wt2 + (size_t)l*512*1024,
            NROWS_X, 512, 1024, 512/128, nullptr,
            nullptr, b2 + l*512, 0, ob,
            last ? nullptr : ssx[1],
            last ? (float*)d_out : nullptr,
            last ? nullptr : hb);
    }

    // ---- edge-region copy (also overwrites ekv scratch; node region written by last FF2) ----
    hipMemcpyAsync((float*)d_out + (size_t)NROWS_X * DIM, hidden + (size_t)NROWS_X * DIM,
                   (size_t)N_EDGES * SEQ * DIM * 4, hipMemcpyDeviceToDevice, stream);
}

// Round 15
// 1329.989 us; speedup vs baseline: 1.2660x; 1.1141x over previous
//
#include <hip/hip_runtime.h>

typedef unsigned short u16;
typedef unsigned int   u32;
typedef u16   u16x8 __attribute__((ext_vector_type(8)));
typedef __bf16 bf16x8 __attribute__((ext_vector_type(8)));
typedef float f32x4 __attribute__((ext_vector_type(4)));
typedef float f32x4v __attribute__((ext_vector_type(4)));

#define N_NODES 4096
#define N_EDGES 16384
#define N_EFEAT 16384
#define SEQ 8
#define DIM 512
#define NLAYER 2
#define NROWS_X (N_NODES*SEQ)     /* 32768 */
#define NROWS_E (N_EDGES*SEQ)     /* 131072 */

__device__ __forceinline__ float b2f(u16 u){ return __uint_as_float(((u32)u)<<16); }
__device__ __forceinline__ u16 f2b(float f){ u32 b=__float_as_uint(f); b += 0x7FFFu + ((b>>16)&1u); return (u16)(b>>16); }

__device__ __forceinline__ void gl16(const u16* g, u16* l) {
    __builtin_amdgcn_global_load_lds((const __attribute__((address_space(1))) void*)g,
                                     (__attribute__((address_space(3))) void*)l, 16, 0, 0);
}

// ---------------- weight transpose + norm-w fold: dst[N][K] = src[K][N] * fold[K] ----------------
__global__ void k_tf(const float* __restrict__ src, u16* __restrict__ dst,
                     const float* __restrict__ fold, int K, int N)
{
    int idx = blockIdx.x * 256 + threadIdx.x;
    if (idx >= K * N) return;
    int c = idx / N, j = idx - c * N;
    float v = src[idx];
    if (fold) v *= fold[c];
    dst[(size_t)j * K + c] = f2b(v);
}

// ---------------- layer-0 row prep: bf16 copy + per-row SUMSQ (wave per row) ----------------
__global__ void k_rowprep(const float* __restrict__ src, u16* __restrict__ dst,
                          float* __restrict__ ssout)
{
    int row  = blockIdx.x * 4 + (threadIdx.x >> 6);
    int lane = threadIdx.x & 63;
    const float* p = src + (size_t)row * DIM;
    f32x4v v0 = *(const f32x4v*)(p + lane * 8);
    f32x4v v1 = *(const f32x4v*)(p + lane * 8 + 4);
    float ss = v0[0]*v0[0]+v0[1]*v0[1]+v0[2]*v0[2]+v0[3]*v0[3]
             + v1[0]*v1[0]+v1[1]*v1[1]+v1[2]*v1[2]+v1[3]*v1[3];
    #pragma unroll
    for (int d = 1; d < 64; d <<= 1) ss += __shfl_xor(ss, d);
    if (lane == 0) ssout[row] = ss;
    u16x8 o;
    #pragma unroll
    for (int i = 0; i < 4; ++i) o[i] = f2b(v0[i]);
    #pragma unroll
    for (int i = 0; i < 4; ++i) o[4+i] = f2b(v1[i]);
    *(u16x8*)(dst + (size_t)row * DIM + lane * 8) = o;
}

// ---------------- feature dedup: ekv[e] = (RMS(feat) @ We)[emap[e]] (RMS commutes w/ gather) --
__global__ void k_mark(const int* __restrict__ emap, int* __restrict__ flag)
{
    int e = blockIdx.x * 256 + threadIdx.x;
    if (e < N_EDGES) flag[emap[e]] = 1;
}
// single block: exclusive scan of flag[16384] -> newid; ulist[newid[m]] = m; ucnt = total
__global__ void k_scanf(const int* __restrict__ flag, int* __restrict__ newid,
                        int* __restrict__ ulist, int* __restrict__ ucnt)
{
    __shared__ int part[256];
    int t = threadIdx.x;
    int base = t * 64;
    int loc[64]; int s = 0;
    #pragma unroll
    for (int i = 0; i < 64; ++i) { loc[i] = s; s += flag[base + i]; }
    part[t] = s; __syncthreads();
    for (int d = 1; d < 256; d <<= 1) {
        int v = (t >= d) ? part[t - d] : 0;
        __syncthreads();
        part[t] += v;
        __syncthreads();
    }
    int pre = (t == 0) ? 0 : part[t - 1];
    #pragma unroll
    for (int i = 0; i < 64; ++i) {
        int m = base + i;
        int id = pre + loc[i];
        newid[m] = id;
        if (flag[m]) ulist[id] = m;
    }
    if (t == 255) ucnt[0] = part[255];
}
__global__ void k_fidx(const int* __restrict__ emap, const int* __restrict__ newid,
                       int* __restrict__ fidx)
{
    int e = blockIdx.x * 256 + threadIdx.x;
    if (e < N_EDGES) fidx[e] = newid[emap[e]];
}
// compact-feature rows: SUMSQ + bf16 copy (wave per row); rows >= ucnt*8 skipped
__global__ void k_featprep(const float* __restrict__ hidden, const int* __restrict__ ulist,
                           const int* __restrict__ ucnt,
                           u16* __restrict__ fbf, float* __restrict__ ssout)
{
    int fr = blockIdx.x * 4 + (threadIdx.x >> 6);   // compact row = j*8+l
    if (fr >= ucnt[0] * SEQ) return;
    int lane = threadIdx.x & 63;
    int j = fr >> 3, l = fr & 7;
    const float* p = hidden + ((size_t)(N_NODES + ulist[j]) * SEQ + l) * DIM;
    f32x4v v0 = *(const f32x4v*)(p + lane * 8);
    f32x4v v1 = *(const f32x4v*)(p + lane * 8 + 4);
    float ss = v0[0]*v0[0]+v0[1]*v0[1]+v0[2]*v0[2]+v0[3]*v0[3]
             + v1[0]*v1[0]+v1[1]*v1[1]+v1[2]*v1[2]+v1[3]*v1[3];
    #pragma unroll
    for (int d = 1; d < 64; d <<= 1) ss += __shfl_xor(ss, d);
    if (lane == 0) ssout[fr] = ss;
    u16x8 o;
    #pragma unroll
    for (int i = 0; i < 4; ++i) o[i] = f2b(v0[i]);
    #pragma unroll
    for (int i = 0; i < 4; ++i) o[4+i] = f2b(v1[i]);
    *(u16x8*)(fbf + (size_t)fr * DIM + lane * 8) = o;
}

// ---------------- CSR build ----------------
__global__ void k_count(const int* __restrict__ dstA, int* __restrict__ cnt)
{
    int e = blockIdx.x * 256 + threadIdx.x;
    if (e < N_EDGES) atomicAdd(&cnt[dstA[e]], 1);
}
__global__ void k_scan(const int* __restrict__ cnt, int* __restrict__ off)
{
    __shared__ int part[256];
    int t = threadIdx.x;
    int base = t * 16;
    int loc[16]; int s = 0;
    #pragma unroll
    for (int i = 0; i < 16; ++i) { loc[i] = s; s += cnt[base + i]; }
    part[t] = s; __syncthreads();
    for (int d = 1; d < 256; d <<= 1) {
        int v = (t >= d) ? part[t - d] : 0;
        __syncthreads();
        part[t] += v;
        __syncthreads();
    }
    int pre = (t == 0) ? 0 : part[t - 1];
    #pragma unroll
    for (int i = 0; i < 16; ++i) off[base + i] = pre + loc[i];
    if (t == 255) off[N_NODES] = part[255];
}
__global__ void k_fill(const int* __restrict__ dstA, const int* __restrict__ off,
                       int* __restrict__ cur, int* __restrict__ elist)
{
    int e = blockIdx.x * 256 + threadIdx.x;
    if (e < N_EDGES) {
        int d = dstA[e];
        int pos = off[d] + atomicAdd(&cur[d], 1);
        elist[pos] = e;
    }
}

// ---------------- bf16 MFMA GEMM body (r12's exact codegen, as a MACRO so the __shared__
// arrays stay first-class LDS — r14's device-fn refactor passed generic pointers and
// regressed all GEMMs ~15%: VALUBusy 21->30). 2-phase __syncthreads, 128x128, BK=32,
// 4 waves of 64x64, gl_lds w=16 dbuf, interleaved-XCD mapping, 0-conflict swizzle,
// fused epilogue (rowscale-from-sumsq, bias, relu, bf16 residual, sumsq-out, f32/bf16 out).
#define GEMM_BODY(BID, A_, B_, N_, K_, GX_, MROWS_, SSIN_, BIAS_, RELU_, RESH_, SSOUT_, OUTF_, OUTH_) \
{                                                                                   \
    int tid  = threadIdx.x;                                                         \
    int lane = tid & 63, wid = tid >> 6;                                            \
    int xcd  = (BID) & 7;                                                           \
    int ii_  = (BID) >> 3;                                                          \
    int colt = ii_ % (GX_);                                                         \
    int rowt = (ii_ / (GX_)) * 8 + xcd;                                             \
    int row0 = rowt * 128, col0 = colt * 128;                                       \
    if ((MROWS_) && row0 >= (MROWS_)[0] * SEQ) return;                              \
    int r0 = wid * 32 + (lane >> 2);                                                \
    int r1 = r0 + 16;                                                               \
    int ce0 = ((lane & 3) * 8) ^ (((r0 >> 1) & 3) << 3);                            \
    int ce1 = ((lane & 3) * 8) ^ (((r1 >> 1) & 3) << 3);                            \
    const u16* ga0 = (A_) + (size_t)(row0 + r0) * (K_) + ce0;                       \
    const u16* ga1 = (A_) + (size_t)(row0 + r1) * (K_) + ce1;                       \
    const u16* gb0 = (B_) + (size_t)(col0 + r0) * (K_) + ce0;                       \
    const u16* gb1 = (B_) + (size_t)(col0 + r1) * (K_) + ce1;                       \
    f32x4 acc[4][4];                                                                \
    _Pragma("unroll")                                                               \
    for (int m = 0; m < 4; ++m)                                                     \
        _Pragma("unroll")                                                           \
        for (int n = 0; n < 4; ++n) { f32x4 z = {0.f,0.f,0.f,0.f}; acc[m][n] = z; } \
    int wr = wid >> 1, wc = wid & 1;                                                \
    int m15 = lane & 15, g = lane >> 4;                                             \
    int arow_l = wr * 64 + m15;                                                     \
    int brow_l = wc * 64 + m15;                                                     \
    int ksw = (g * 8) ^ (((m15 >> 1) & 3) << 3);                                    \
    int NT = (K_) / 32;                                                             \
    {                                                                               \
        gl16(ga0, &ldsA[0][wid * 1024]);                                            \
        gl16(ga1, &ldsA[0][wid * 1024 + 512]);                                      \
        gl16(gb0, &ldsB[0][wid * 1024]);                                            \
        gl16(gb1, &ldsB[0][wid * 1024 + 512]);                                      \
    }                                                                               \
    int cur = 0;                                                                    \
    for (int kt = 0; kt < NT; ++kt) {                                               \
        __syncthreads();                                                            \
        if (kt + 1 < NT) {                                                          \
            int ko = (kt + 1) * 32, bf_ = cur ^ 1;                                  \
            gl16(ga0 + ko, &ldsA[bf_][wid * 1024]);                                 \
            gl16(ga1 + ko, &ldsA[bf_][wid * 1024 + 512]);                           \
            gl16(gb0 + ko, &ldsB[bf_][wid * 1024]);                                 \
            gl16(gb1 + ko, &ldsB[bf_][wid * 1024 + 512]);                           \
        }                                                                           \
        bf16x8 af[4], bfr[4];                                                       \
        _Pragma("unroll")                                                           \
        for (int m = 0; m < 4; ++m)                                                 \
            af[m] = *(const bf16x8*)&ldsA[cur][(arow_l + m * 16) * 32 + ksw];       \
        _Pragma("unroll")                                                           \
        for (int n = 0; n < 4; ++n)                                                 \
            bfr[n] = *(const bf16x8*)&ldsB[cur][(brow_l + n * 16) * 32 + ksw];      \
        _Pragma("unroll")                                                           \
        for (int m = 0; m < 4; ++m)                                                 \
            _Pragma("unroll")                                                       \
            for (int n = 0; n < 4; ++n)                                             \
                acc[m][n] = __builtin_amdgcn_mfma_f32_16x16x32_bf16(af[m], bfr[n], acc[m][n], 0, 0, 0); \
        cur ^= 1;                                                                   \
    }                                                                               \
    _Pragma("unroll")                                                               \
    for (int m = 0; m < 4; ++m) {                                                   \
        _Pragma("unroll")                                                           \
        for (int j = 0; j < 4; ++j) {                                               \
            int row = row0 + wr * 64 + m * 16 + g * 4 + j;                          \
            float sc = 0.f;                                                         \
            if (SSIN_) sc = rsqrtf((SSIN_)[row] * (1.f / (float)DIM) + 1e-6f);      \
            float ssa = 0.f;                                                        \
            _Pragma("unroll")                                                       \
            for (int n = 0; n < 4; ++n) {                                           \
                int col = col0 + wc * 64 + n * 16 + m15;                            \
                float v = acc[m][n][j];                                             \
                if (SSIN_) v *= sc;                                                 \
                if (BIAS_) v += (BIAS_)[col];                                       \
                if (RELU_) v = fmaxf(v, 0.f);                                       \
                if (RESH_) v += b2f((RESH_)[(size_t)row * (N_) + col]);             \
                if (OUTF_) (OUTF_)[(size_t)row * (N_) + col] = v;                   \
                if (OUTH_) (OUTH_)[(size_t)row * (N_) + col] = f2b(v);              \
                ssa += v * v;                                                       \
            }                                                                       \
            if (SSOUT_) {                                                           \
                ssa += __shfl_xor(ssa, 1);                                          \
                ssa += __shfl_xor(ssa, 2);                                          \
                ssa += __shfl_xor(ssa, 4);                                          \
                ssa += __shfl_xor(ssa, 8);                                          \
                if (m15 == 0) atomicAdd(&(SSOUT_)[row], ssa);                       \
            }                                                                       \
        }                                                                           \
    }                                                                               \
}

__global__ __launch_bounds__(256, 2) void k_gemm(
    const u16* __restrict__ A, const u16* __restrict__ B,
    int M, int N, int K, int gx, const int* __restrict__ mrows,
    const float* __restrict__ ssin, const float* __restrict__ bias, int relu,
    const u16* __restrict__ resH, float* __restrict__ ssout,
    float* __restrict__ outF, u16* __restrict__ outH)
{
    __shared__ u16 ldsA[2][128 * 32];
    __shared__ u16 ldsB[2][128 * 32];
    GEMM_BODY(blockIdx.x, A, B, N, K, gx, mrows, ssin, bias, relu, resH, ssout, outF, outH)
}

// two independent GEMMs, one dispatch (blocks < nb0 -> set 0; else set 1). nb0 % 8 == 0
// keeps the per-half XCD mapping aligned; fills GEMM-0's drain tail with GEMM-1 blocks.
__global__ __launch_bounds__(256, 2) void k_gemm2(
    int nb0,
    const u16* __restrict__ A0, const u16* __restrict__ B0,
    int N0, int K0, int gx0, const int* __restrict__ mrows0,
    const float* __restrict__ ssin0, const float* __restrict__ bias0, int relu0,
    const u16* __restrict__ resH0, float* __restrict__ ssout0,
    float* __restrict__ outF0, u16* __restrict__ outH0,
    const u16* __restrict__ A1, const u16* __restrict__ B1,
    int N1, int K1, int gx1, const int* __restrict__ mrows1,
    const float* __restrict__ ssin1, const float* __restrict__ bias1, int relu1,
    const u16* __restrict__ resH1, float* __restrict__ ssout1,
    float* __restrict__ outF1, u16* __restrict__ outH1)
{
    __shared__ u16 ldsA[2][128 * 32];
    __shared__ u16 ldsB[2][128 * 32];
    if ((int)blockIdx.x < nb0) {
        GEMM_BODY(blockIdx.x, A0, B0, N0, K0, gx0, mrows0, ssin0, bias0, relu0, resH0, ssout0, outF0, outH0)
    } else {
        int bid = blockIdx.x - nb0;
        GEMM_BODY(bid, A1, B1, N1, K1, gx1, mrows1, ssin1, bias1, relu1, resH1, ssout1, outF1, outH1)
    }
}

// ---------------- per-node attention: online segment softmax + aggregate (RoPE eliminated:
// both sides rotated by the same position l -> orthogonal rotation cancels in the dot).
// Edge features indexed via compact fidx[e] (dedup'd fkv table). ------
__global__ __launch_bounds__(256, 2) void k_attn(
    const u16* __restrict__ qkv, const u16* __restrict__ ekv,
    const int* __restrict__ srcA, const int* __restrict__ fidx,
    const int* __restrict__ off, const int* __restrict__ elist,
    u16* __restrict__ agg)
{
    int n = blockIdx.x;
    int t = threadIdx.x;
    int pair = t >> 2, sub = t & 3;
    int l = pair >> 3, hd = pair & 7;
    int doff = hd * 64 + sub * 16;

    size_t qrow = ((size_t)n * SEQ + l) * 1536;
    float qi[16];
    {
        u16x8 qa = *(const u16x8*)&qkv[qrow + doff];
        u16x8 qb = *(const u16x8*)&qkv[qrow + doff + 8];
        #pragma unroll
        for (int i = 0; i < 8; ++i) { qi[i] = b2f(qa[i]); qi[i + 8] = b2f(qb[i]); }
    }

    float mrun = -INFINITY, s = 0.f;
    float av[16];
    #pragma unroll
    for (int i = 0; i < 16; ++i) av[i] = 0.f;

    int e0 = off[n], e1 = off[n + 1];
    for (int ii = e0; ii < e1; ++ii) {
        int e = elist[ii];
        int es = srcA[e];
        size_t krow = ((size_t)es * SEQ + l) * 1536 + 512;
        size_t erow = ((size_t)fidx[e] * SEQ + l) * 1024;

        u16x8 ka = *(const u16x8*)&qkv[krow + doff];
        u16x8 kb = *(const u16x8*)&qkv[krow + doff + 8];
        u16x8 ea = *(const u16x8*)&ekv[erow + doff];
        u16x8 eb = *(const u16x8*)&ekv[erow + doff + 8];

        float dot = 0.f;
        #pragma unroll
        for (int i = 0; i < 8; ++i) {
            dot += qi[i]     * (b2f(ka[i]) + b2f(ea[i]));
            dot += qi[i + 8] * (b2f(kb[i]) + b2f(eb[i]));
        }
        dot += __shfl_xor(dot, 1);
        dot += __shfl_xor(dot, 2);
        float alpha = dot * 0.125f;     // 1/sqrt(64)

        float mn = fmaxf(mrun, alpha);
        float f = expf(mrun - mn);      // mrun=-inf -> 0
        float p = expf(alpha - mn);
        s = s * f + p;

        u16x8 va  = *(const u16x8*)&qkv[krow + 512 + doff];
        u16x8 vb  = *(const u16x8*)&qkv[krow + 512 + doff + 8];
        u16x8 eva = *(const u16x8*)&ekv[erow + 512 + doff];
        u16x8 evb = *(const u16x8*)&ekv[erow + 512 + doff + 8];
        #pragma unroll
        for (int i = 0; i < 8; ++i) {
            av[i]     = av[i]     * f + p * (b2f(va[i]) + b2f(eva[i]));
            av[i + 8] = av[i + 8] * f + p * (b2f(vb[i]) + b2f(evb[i]));
        }
        mrun = mn;
    }

    float inv = 1.f / (s + 1e-16f);
    size_t orow = ((size_t)n * SEQ + l) * DIM + doff;
    #pragma unroll
    for (int i = 0; i < 16; ++i) agg[orow + i] = f2b(av[i] * inv);
}

extern "C" void kernel_launch(void* const* d_in, const int* in_sizes, int n_in,
                              void* d_out, int out_size, void* d_ws, size_t ws_size,
                              hipStream_t stream)
{
    const float* hidden = (const float*)d_in[0];
    const int*   eidx   = (const int*)d_in[1];
    const int*   srcA   = eidx;              // edge_index[0]
    const int*   dstA   = eidx + N_EDGES;    // edge_index[1]
    const int*   emap   = (const int*)d_in[2];
    const float* W_qkv  = (const float*)d_in[4];
    const float* W_e    = (const float*)d_in[5];
    const float* W_o    = (const float*)d_in[6];
    const float* xw     = (const float*)d_in[7];
    const float* xew    = (const float*)d_in[8];
    const float* pw     = (const float*)d_in[9];
    const float* W1     = (const float*)d_in[10];
    const float* b1     = (const float*)d_in[11];
    const float* W2     = (const float*)d_in[12];
    const float* b2     = (const float*)d_in[13];

    char* w = (char*)d_ws;
    auto alloc = [&](size_t bytes) { char* p = w; w += (bytes + 255) & ~(size_t)255; return p; };
    u16*  WtQKV  = (u16*)alloc((size_t)NLAYER * 1536 * 512 * 2);
    u16*  WtE    = (u16*)alloc((size_t)NLAYER * 1024 * 512 * 2);
    u16*  WtO    = (u16*)alloc((size_t)NLAYER * 512 * 512 * 2);
    u16*  Wt1    = (u16*)alloc((size_t)NLAYER * 1024 * 512 * 2);
    u16*  Wt2    = (u16*)alloc((size_t)NLAYER * 512 * 1024 * 2);
    float* ssx0  = (float*)alloc((size_t)NROWS_X * 4);
    float* ssx1  = (float*)alloc((size_t)NROWS_X * 4);
    float* ssp0  = (float*)alloc((size_t)NROWS_X * 4);
    float* ssp1  = (float*)alloc((size_t)NROWS_X * 4);
    float* s_f   = (float*)alloc((size_t)NROWS_E * 4);
    int*  cnt    = (int*)alloc((N_NODES + 1) * 4);
    int*  off    = (int*)alloc((N_NODES + 1) * 4);
    int*  cur    = (int*)alloc(N_NODES * 4);
    int*  elist  = (int*)alloc(N_EDGES * 4);
    int*  flag   = (int*)alloc(N_EFEAT * 4);
    int*  newid  = (int*)alloc(N_EFEAT * 4);
    int*  ulist  = (int*)alloc(N_EFEAT * 4);
    int*  fidx   = (int*)alloc(N_EDGES * 4);
    int*  ucnt   = (int*)alloc(256);
    u16*  hb     = (u16*)alloc((size_t)NROWS_X * DIM * 2);
    u16*  ob     = (u16*)alloc((size_t)NROWS_X * DIM * 2);
    u16*  fbf    = (u16*)alloc((size_t)NROWS_E * DIM * 2);
    u16*  qkv    = (u16*)alloc((size_t)NROWS_X * 1536 * 2);
    u16*  aggB   = (u16*)alloc((size_t)NROWS_X * DIM * 2);
    u16*  ffmid  = (u16*)alloc((size_t)NROWS_X * 1024 * 2);
    // ekv scratch lives in d_out's edge region (exact size match: 131072*1024*2B = 16384*4096*4B)
    u16*  ekv    = (u16*)((float*)d_out + (size_t)NROWS_X * DIM);
    float* ssx[2] = { ssx0, ssx1 };
    float* ssp[2] = { ssp0, ssp1 };

    // ---- one-time prep ----
    for (int l = 0; l < NLAYER; ++l) {
        k_tf<<<(512*1536 + 255)/256, 256, 0, stream>>>(W_qkv + (size_t)l*512*1536, WtQKV + (size_t)l*1536*512, xw  + l*512, 512, 1536);
        k_tf<<<(512*1024 + 255)/256, 256, 0, stream>>>(W_e   + (size_t)l*512*1024, WtE   + (size_t)l*1024*512, xew + l*512, 512, 1024);
        k_tf<<<(512*512  + 255)/256, 256, 0, stream>>>(W_o   + (size_t)l*512*512,  WtO   + (size_t)l*512*512,  nullptr,    512, 512);
        k_tf<<<(512*1024 + 255)/256, 256, 0, stream>>>(W1    + (size_t)l*512*1024, Wt1   + (size_t)l*1024*512, pw  + l*512, 512, 1024);
        k_tf<<<(1024*512 + 255)/256, 256, 0, stream>>>(W2    + (size_t)l*1024*512, Wt2   + (size_t)l*512*1024, nullptr,    1024, 512);
    }
    // zero atomic-sumsq accumulators (re-zeroed every call; graph-replay safe)
    hipMemsetAsync(ssx1, 0, NROWS_X * 4, stream);
    hipMemsetAsync(ssp0, 0, NROWS_X * 4, stream);
    hipMemsetAsync(ssp1, 0, NROWS_X * 4, stream);
    // dedup + compact-feature prep
    hipMemsetAsync(flag, 0, N_EFEAT * 4, stream);
    k_mark<<<N_EDGES/256, 256, 0, stream>>>(emap, flag);
    k_scanf<<<1, 256, 0, stream>>>(flag, newid, ulist, ucnt);
    k_fidx<<<N_EDGES/256, 256, 0, stream>>>(emap, newid, fidx);
    k_featprep<<<NROWS_E/4, 256, 0, stream>>>(hidden, ulist, ucnt, fbf, s_f);
    // CSR by dst
    hipMemsetAsync(cnt, 0, (N_NODES + 1) * 4, stream);
    hipMemsetAsync(cur, 0, N_NODES * 4, stream);
    k_count<<<N_EDGES/256, 256, 0, stream>>>(dstA, cnt);
    k_scan<<<1, 256, 0, stream>>>(cnt, off);
    k_fill<<<N_EDGES/256, 256, 0, stream>>>(dstA, off, cur, elist);
    // layer-0 node prep: bf16 copy + sumsq
    k_rowprep<<<NROWS_X/4, 256, 0, stream>>>(hidden, hb, ssx0);

    const int nbQ = (NROWS_X/128)*(1536/128);   // 3072 (div by 8)
    const int nbE = (NROWS_E/128)*(1024/128);   // 8192

    // ---- layers (all state bf16; RMS scales from fused sumsq) ----
    for (int l = 0; l < NLAYER; ++l) {
        int last = (l == NLAYER - 1);
        // qkv = rms(h)@Wqkv  +  ekv = rms(feat)@We (dedup'd) — ONE dispatch, tail-filled
        k_gemm2<<<nbQ + nbE, 256, 0, stream>>>(nbQ,
            hb, WtQKV + (size_t)l*1536*512, 1536, 512, 1536/128, nullptr,
            ssx[l], nullptr, 0, nullptr, nullptr, nullptr, qkv,
            fbf, WtE + (size_t)l*1024*512, 1024, 512, 1024/128, ucnt,
            s_f, nullptr, 0, nullptr, nullptr, nullptr, ekv);
        k_attn<<<N_NODES, 256, 0, stream>>>(qkv, ekv, srcA, fidx, off, elist, aggB);
        // out = h + agg@Wo   -> ob (bf16) + sumsq(out) -> ssp[l]
        k_gemm<<<(NROWS_X/128)*(512/128), 256, 0, stream>>>(aggB, WtO + (size_t)l*512*512,
            NROWS_X, 512, 512, 512/128, nullptr,
            nullptr, nullptr, 0, hb, ssp[l], nullptr, ob);
        // ffmid = relu(rms(out)@W1 + b1)   (rowscale from ssp[l])
        k_gemm<<<(NROWS_X/128)*(1024/128), 256, 0, stream>>>(ob, Wt1 + (size_t)l*1024*512,
            NROWS_X, 1024, 512, 1024/128, nullptr,
            ssp[l], b1 + l*1024, 1, nullptr, nullptr, nullptr, ffmid);
        // h' = out + ffmid@W2 + b2  -> hb (bf16) + sumsq -> ssx[l+1]; last: fp32 d_out
        k_gemm<<<(NROWS_X/128)*(512/128), 256, 0, stream>>>(ffmid, Wt2 + (size_t)l*512*1024,
            NROWS_X, 512, 1024, 512/128, nullptr,
            nullptr, b2 + l*512, 0, ob,
            last ? nullptr : ssx[1],
            last ? (float*)d_out : nullptr,
            last ? nullptr : hb);
    }

    // ---- edge-region copy (also overwrites ekv scratch; node region written by last FF2) ----
    hipMemcpyAsync((float*)d_out + (size_t)NROWS_X * DIM, hidden + (size_t)NROWS_X * DIM,
                   (size_t)N_EDGES * SEQ * DIM * 4, hipMemcpyDeviceToDevice, stream);
}

// Round 16
// 1319.835 us; speedup vs baseline: 1.2757x; 1.0077x over previous
//
#include <hip/hip_runtime.h>

typedef unsigned short u16;
typedef unsigned int   u32;
typedef u16   u16x8 __attribute__((ext_vector_type(8)));
typedef __bf16 bf16x8 __attribute__((ext_vector_type(8)));
typedef float f32x4 __attribute__((ext_vector_type(4)));
typedef float f32x4v __attribute__((ext_vector_type(4)));

#define N_NODES 4096
#define N_EDGES 16384
#define N_EFEAT 16384
#define SEQ 8
#define DIM 512
#define NLAYER 2
#define NROWS_X (N_NODES*SEQ)     /* 32768 */
#define NROWS_E (N_EDGES*SEQ)     /* 131072 */

__device__ __forceinline__ float b2f(u16 u){ return __uint_as_float(((u32)u)<<16); }
__device__ __forceinline__ u16 f2b(float f){ u32 b=__float_as_uint(f); b += 0x7FFFu + ((b>>16)&1u); return (u16)(b>>16); }

__device__ __forceinline__ void gl16(const u16* g, u16* l) {
    __builtin_amdgcn_global_load_lds((const __attribute__((address_space(1))) void*)g,
                                     (__attribute__((address_space(3))) void*)l, 16, 0, 0);
}

// ---------------- ALL weight transposes (+norm-w fold) + zero-fills, ONE dispatch ----------------
// per layer: qkv 3072 blk | e 2048 | o 1024 | w1 2048 | w2 2048  (= 10240; x2 layers = 20480)
// then: ssx1 128 | ssp0 128 | ssp1 128 | flag 64  -> grid 20928
#define TF_SEG(CNT, SRC, DST, FOLD, KK, NN)                                   \
    if (b < (CNT)) {                                                          \
        int idx = b * 256 + threadIdx.x;                                      \
        int c = idx / (NN), j = idx - c * (NN);                               \
        float v = (SRC)[idx];                                                 \
        if (FOLD) v *= (FOLD)[c];                                             \
        (DST)[(size_t)j * (KK) + c] = f2b(v);                                 \
        return;                                                               \
    }                                                                         \
    b -= (CNT);

__global__ void k_tfall(const float* __restrict__ Wqkv, const float* __restrict__ We,
                        const float* __restrict__ Wo,   const float* __restrict__ W1,
                        const float* __restrict__ W2,
                        const float* __restrict__ xw, const float* __restrict__ xew,
                        const float* __restrict__ pw,
                        u16* __restrict__ WtQKV, u16* __restrict__ WtE, u16* __restrict__ WtO,
                        u16* __restrict__ Wt1, u16* __restrict__ Wt2,
                        float* __restrict__ z0, float* __restrict__ z1,
                        float* __restrict__ z2, int* __restrict__ zf)
{
    int b = blockIdx.x;
    if (b >= 20480) {
        b -= 20480;
        if (b < 128) { z0[b * 256 + threadIdx.x] = 0.f; return; }
        b -= 128;
        if (b < 128) { z1[b * 256 + threadIdx.x] = 0.f; return; }
        b -= 128;
        if (b < 128) { z2[b * 256 + threadIdx.x] = 0.f; return; }
        b -= 128;
        zf[b * 256 + threadIdx.x] = 0; return;
    }
    int l = b / 10240; b -= l * 10240;
    TF_SEG(3072, Wqkv + (size_t)l*512*1536, WtQKV + (size_t)l*1536*512, xw  + l*512, 512, 1536)
    TF_SEG(2048, We   + (size_t)l*512*1024, WtE   + (size_t)l*1024*512, xew + l*512, 512, 1024)
    TF_SEG(1024, Wo   + (size_t)l*512*512,  WtO   + (size_t)l*512*512,  (const float*)nullptr, 512, 512)
    TF_SEG(2048, W1   + (size_t)l*512*1024, Wt1   + (size_t)l*1024*512, pw  + l*512, 512, 1024)
    TF_SEG(2048, W2   + (size_t)l*1024*512, Wt2   + (size_t)l*512*1024, (const float*)nullptr, 1024, 512)
}

// ---------------- merged prep: compact-feature rows (SUMSQ+bf16) + layer-0 node rows ----------
__global__ void k_prep(const float* __restrict__ hidden, const int* __restrict__ ulist,
                       const int* __restrict__ ucnt,
                       u16* __restrict__ fbf, float* __restrict__ s_f,
                       u16* __restrict__ hb, float* __restrict__ ssx0)
{
    int lane = threadIdx.x & 63;
    const float* p;
    u16* dst; float* ssout; int orow;
    if (blockIdx.x < NROWS_E / 4) {
        int fr = blockIdx.x * 4 + (threadIdx.x >> 6);   // compact row = j*8+l
        if (fr >= ucnt[0] * SEQ) return;
        int j = fr >> 3, l = fr & 7;
        p = hidden + ((size_t)(N_NODES + ulist[j]) * SEQ + l) * DIM;
        dst = fbf + (size_t)fr * DIM; ssout = s_f; orow = fr;
    } else {
        int row = (blockIdx.x - NROWS_E / 4) * 4 + (threadIdx.x >> 6);
        p = hidden + (size_t)row * DIM;
        dst = hb + (size_t)row * DIM; ssout = ssx0; orow = row;
    }
    f32x4v v0 = *(const f32x4v*)(p + lane * 8);
    f32x4v v1 = *(const f32x4v*)(p + lane * 8 + 4);
    float ss = v0[0]*v0[0]+v0[1]*v0[1]+v0[2]*v0[2]+v0[3]*v0[3]
             + v1[0]*v1[0]+v1[1]*v1[1]+v1[2]*v1[2]+v1[3]*v1[3];
    #pragma unroll
    for (int d = 1; d < 64; d <<= 1) ss += __shfl_xor(ss, d);
    if (lane == 0) ssout[orow] = ss;
    u16x8 o;
    #pragma unroll
    for (int i = 0; i < 4; ++i) o[i] = f2b(v0[i]);
    #pragma unroll
    for (int i = 0; i < 4; ++i) o[4+i] = f2b(v1[i]);
    *(u16x8*)(dst + lane * 8) = o;
}

// ---------------- feature dedup helpers ----------------
__global__ void k_mark(const int* __restrict__ emap, int* __restrict__ flag)
{
    int e = blockIdx.x * 256 + threadIdx.x;
    if (e < N_EDGES) flag[emap[e]] = 1;
}
__global__ void k_scanf(const int* __restrict__ flag, int* __restrict__ newid,
                        int* __restrict__ ulist, int* __restrict__ ucnt)
{
    __shared__ int part[256];
    int t = threadIdx.x;
    int base = t * 64;
    int loc[64]; int s = 0;
    #pragma unroll
    for (int i = 0; i < 64; ++i) { loc[i] = s; s += flag[base + i]; }
    part[t] = s; __syncthreads();
    for (int d = 1; d < 256; d <<= 1) {
        int v = (t >= d) ? part[t - d] : 0;
        __syncthreads();
        part[t] += v;
        __syncthreads();
    }
    int pre = (t == 0) ? 0 : part[t - 1];
    #pragma unroll
    for (int i = 0; i < 64; ++i) {
        int m = base + i;
        int id = pre + loc[i];
        newid[m] = id;
        if (flag[m]) ulist[id] = m;
    }
    if (t == 255) ucnt[0] = part[255];
}
__global__ void k_fidx(const int* __restrict__ emap, const int* __restrict__ newid,
                       int* __restrict__ fidx)
{
    int e = blockIdx.x * 256 + threadIdx.x;
    if (e < N_EDGES) fidx[e] = newid[emap[e]];
}

// ---------------- CSR build ----------------
__global__ void k_count(const int* __restrict__ dstA, int* __restrict__ cnt)
{
    int e = blockIdx.x * 256 + threadIdx.x;
    if (e < N_EDGES) atomicAdd(&cnt[dstA[e]], 1);
}
__global__ void k_scan(const int* __restrict__ cnt, int* __restrict__ off)
{
    __shared__ int part[256];
    int t = threadIdx.x;
    int base = t * 16;
    int loc[16]; int s = 0;
    #pragma unroll
    for (int i = 0; i < 16; ++i) { loc[i] = s; s += cnt[base + i]; }
    part[t] = s; __syncthreads();
    for (int d = 1; d < 256; d <<= 1) {
        int v = (t >= d) ? part[t - d] : 0;
        __syncthreads();
        part[t] += v;
        __syncthreads();
    }
    int pre = (t == 0) ? 0 : part[t - 1];
    #pragma unroll
    for (int i = 0; i < 16; ++i) off[base + i] = pre + loc[i];
    if (t == 255) off[N_NODES] = part[255];
}
__global__ void k_fill(const int* __restrict__ dstA, const int* __restrict__ off,
                       int* __restrict__ cur, int* __restrict__ elist)
{
    int e = blockIdx.x * 256 + threadIdx.x;
    if (e < N_EDGES) {
        int d = dstA[e];
        int pos = off[d] + atomicAdd(&cur[d], 1);
        elist[pos] = e;
    }
}

// ---------------- bf16 MFMA GEMM body (r15's proven macro codegen): 2-phase __syncthreads,
// 128x128 tile, BK=32, 4 waves of 64x64, gl_lds w=16 dbuf, interleaved-XCD mapping,
// 0-conflict swizzle, fused epilogue.
#define GEMM_BODY(BID, A_, B_, N_, K_, GX_, MROWS_, SSIN_, BIAS_, RELU_, RESH_, SSOUT_, OUTF_, OUTH_) \
{                                                                                   \
    int tid  = threadIdx.x;                                                         \
    int lane = tid & 63, wid = tid >> 6;                                            \
    int xcd  = (BID) & 7;                                                           \
    int ii_  = (BID) >> 3;                                                          \
    int colt = ii_ % (GX_);                                                         \
    int rowt = (ii_ / (GX_)) * 8 + xcd;                                             \
    int row0 = rowt * 128, col0 = colt * 128;                                       \
    if ((MROWS_) && row0 >= (MROWS_)[0] * SEQ) return;                              \
    int r0 = wid * 32 + (lane >> 2);                                                \
    int r1 = r0 + 16;                                                               \
    int ce0 = ((lane & 3) * 8) ^ (((r0 >> 1) & 3) << 3);                            \
    int ce1 = ((lane & 3) * 8) ^ (((r1 >> 1) & 3) << 3);                            \
    const u16* ga0 = (A_) + (size_t)(row0 + r0) * (K_) + ce0;                       \
    const u16* ga1 = (A_) + (size_t)(row0 + r1) * (K_) + ce1;                       \
    const u16* gb0 = (B_) + (size_t)(col0 + r0) * (K_) + ce0;                       \
    const u16* gb1 = (B_) + (size_t)(col0 + r1) * (K_) + ce1;                       \
    f32x4 acc[4][4];                                                                \
    _Pragma("unroll")                                                               \
    for (int m = 0; m < 4; ++m)                                                     \
        _Pragma("unroll")                                                           \
        for (int n = 0; n < 4; ++n) { f32x4 z = {0.f,0.f,0.f,0.f}; acc[m][n] = z; } \
    int wr = wid >> 1, wc = wid & 1;                                                \
    int m15 = lane & 15, g = lane >> 4;                                             \
    int arow_l = wr * 64 + m15;                                                     \
    int brow_l = wc * 64 + m15;                                                     \
    int ksw = (g * 8) ^ (((m15 >> 1) & 3) << 3);                                    \
    int NT = (K_) / 32;                                                             \
    {                                                                               \
        gl16(ga0, &ldsA[0][wid * 1024]);                                            \
        gl16(ga1, &ldsA[0][wid * 1024 + 512]);                                      \
        gl16(gb0, &ldsB[0][wid * 1024]);                                            \
        gl16(gb1, &ldsB[0][wid * 1024 + 512]);                                      \
    }                                                                               \
    int cur = 0;                                                                    \
    for (int kt = 0; kt < NT; ++kt) {                                               \
        __syncthreads();                                                            \
        if (kt + 1 < NT) {                                                          \
            int ko = (kt + 1) * 32, bf_ = cur ^ 1;                                  \
            gl16(ga0 + ko, &ldsA[bf_][wid * 1024]);                                 \
            gl16(ga1 + ko, &ldsA[bf_][wid * 1024 + 512]);                           \
            gl16(gb0 + ko, &ldsB[bf_][wid * 1024]);                                 \
            gl16(gb1 + ko, &ldsB[bf_][wid * 1024 + 512]);                           \
        }                                                                           \
        bf16x8 af[4], bfr[4];                                                       \
        _Pragma("unroll")                                                           \
        for (int m = 0; m < 4; ++m)                                                 \
            af[m] = *(const bf16x8*)&ldsA[cur][(arow_l + m * 16) * 32 + ksw];       \
        _Pragma("unroll")                                                           \
        for (int n = 0; n < 4; ++n)                                                 \
            bfr[n] = *(const bf16x8*)&ldsB[cur][(brow_l + n * 16) * 32 + ksw];      \
        _Pragma("unroll")                                                           \
        for (int m = 0; m < 4; ++m)                                                 \
            _Pragma("unroll")                                                       \
            for (int n = 0; n < 4; ++n)                                             \
                acc[m][n] = __builtin_amdgcn_mfma_f32_16x16x32_bf16(af[m], bfr[n], acc[m][n], 0, 0, 0); \
        cur ^= 1;                                                                   \
    }                                                                               \
    _Pragma("unroll")                                                               \
    for (int m = 0; m < 4; ++m) {                                                   \
        _Pragma("unroll")                                                           \
        for (int j = 0; j < 4; ++j) {                                               \
            int row = row0 + wr * 64 + m * 16 + g * 4 + j;                          \
            float sc = 0.f;                                                         \
            if (SSIN_) sc = rsqrtf((SSIN_)[row] * (1.f / (float)DIM) + 1e-6f);      \
            float ssa = 0.f;                                                        \
            _Pragma("unroll")                                                       \
            for (int n = 0; n < 4; ++n) {                                           \
                int col = col0 + wc * 64 + n * 16 + m15;                            \
                float v = acc[m][n][j];                                             \
                if (SSIN_) v *= sc;                                                 \
                if (BIAS_) v += (BIAS_)[col];                                       \
                if (RELU_) v = fmaxf(v, 0.f);                                       \
                if (RESH_) v += b2f((RESH_)[(size_t)row * (N_) + col]);             \
                if (OUTF_) (OUTF_)[(size_t)row * (N_) + col] = v;                   \
                if (OUTH_) (OUTH_)[(size_t)row * (N_) + col] = f2b(v);              \
                ssa += v * v;                                                       \
            }                                                                       \
            if (SSOUT_) {                                                           \
                ssa += __shfl_xor(ssa, 1);                                          \
                ssa += __shfl_xor(ssa, 2);                                          \
                ssa += __shfl_xor(ssa, 4);                                          \
                ssa += __shfl_xor(ssa, 8);                                          \
                if (m15 == 0) atomicAdd(&(SSOUT_)[row], ssa);                       \
            }                                                                       \
        }                                                                           \
    }                                                                               \
}

__global__ __launch_bounds__(256, 2) void k_gemm(
    const u16* __restrict__ A, const u16* __restrict__ B,
    int M, int N, int K, int gx, const int* __restrict__ mrows,
    const float* __restrict__ ssin, const float* __restrict__ bias, int relu,
    const u16* __restrict__ resH, float* __restrict__ ssout,
    float* __restrict__ outF, u16* __restrict__ outH)
{
    __shared__ u16 ldsA[2][128 * 32];
    __shared__ u16 ldsB[2][128 * 32];
    GEMM_BODY(blockIdx.x, A, B, N, K, gx, mrows, ssin, bias, relu, resH, ssout, outF, outH)
}

// two independent GEMMs, one dispatch (blocks < nb0 -> set 0; else set 1). nb0 % 8 == 0.
__global__ __launch_bounds__(256, 2) void k_gemm2(
    int nb0,
    const u16* __restrict__ A0, const u16* __restrict__ B0,
    int N0, int K0, int gx0, const int* __restrict__ mrows0,
    const float* __restrict__ ssin0, const float* __restrict__ bias0, int relu0,
    const u16* __restrict__ resH0, float* __restrict__ ssout0,
    float* __restrict__ outF0, u16* __restrict__ outH0,
    const u16* __restrict__ A1, const u16* __restrict__ B1,
    int N1, int K1, int gx1, const int* __restrict__ mrows1,
    const float* __restrict__ ssin1, const float* __restrict__ bias1, int relu1,
    const u16* __restrict__ resH1, float* __restrict__ ssout1,
    float* __restrict__ outF1, u16* __restrict__ outH1)
{
    __shared__ u16 ldsA[2][128 * 32];
    __shared__ u16 ldsB[2][128 * 32];
    if ((int)blockIdx.x < nb0) {
        GEMM_BODY(blockIdx.x, A0, B0, N0, K0, gx0, mrows0, ssin0, bias0, relu0, resH0, ssout0, outF0, outH0)
    } else {
        int bid = blockIdx.x - nb0;
        GEMM_BODY(bid, A1, B1, N1, K1, gx1, mrows1, ssin1, bias1, relu1, resH1, ssout1, outF1, outH1)
    }
}

// GEMM + bulk f32 copy in one dispatch (overlaps the 256 MB edge-region output copy with
// the last-layer Wo GEMM; copy is legal here — ekv's last reader was this layer's attn).
// Copy half: 2048 blocks x 256 thr x 32 float4 (grid-strided, coalesced) = 64M floats.
__global__ __launch_bounds__(256, 2) void k_gemm_copy(
    int nb0,
    const u16* __restrict__ A, const u16* __restrict__ B,
    int N, int K, int gx,
    const float* __restrict__ ssin, const float* __restrict__ bias, int relu,
    const u16* __restrict__ resH, float* __restrict__ ssout,
    float* __restrict__ outF, u16* __restrict__ outH,
    const f32x4v* __restrict__ csrc, f32x4v* __restrict__ cdst)
{
    __shared__ u16 ldsA[2][128 * 32];
    __shared__ u16 ldsB[2][128 * 32];
    if ((int)blockIdx.x < nb0) {
        GEMM_BODY(blockIdx.x, A, B, N, K, gx, (const int*)nullptr, ssin, bias, relu, resH, ssout, outF, outH)
    } else {
        size_t t = (size_t)(blockIdx.x - nb0) * 256 + threadIdx.x;   // 524288 threads
        #pragma unroll
        for (int k = 0; k < 32; ++k)
            cdst[t + (size_t)k * 524288] = csrc[t + (size_t)k * 524288];
    }
}

// ---------------- per-node attention: online segment softmax + aggregate (RoPE eliminated:
// both sides rotated by the same position l -> orthogonal rotation cancels in the dot).
// Edge features indexed via compact fidx[e] (dedup'd fkv table). ------
__global__ __launch_bounds__(256, 2) void k_attn(
    const u16* __restrict__ qkv, const u16* __restrict__ ekv,
    const int* __restrict__ srcA, const int* __restrict__ fidx,
    const int* __restrict__ off, const int* __restrict__ elist,
    u16* __restrict__ agg)
{
    int n = blockIdx.x;
    int t = threadIdx.x;
    int pair = t >> 2, sub = t & 3;
    int l = pair >> 3, hd = pair & 7;
    int doff = hd * 64 + sub * 16;

    size_t qrow = ((size_t)n * SEQ + l) * 1536;
    float qi[16];
    {
        u16x8 qa = *(const u16x8*)&qkv[qrow + doff];
        u16x8 qb = *(const u16x8*)&qkv[qrow + doff + 8];
        #pragma unroll
        for (int i = 0; i < 8; ++i) { qi[i] = b2f(qa[i]); qi[i + 8] = b2f(qb[i]); }
    }

    float mrun = -INFINITY, s = 0.f;
    float av[16];
    #pragma unroll
    for (int i = 0; i < 16; ++i) av[i] = 0.f;

    int e0 = off[n], e1 = off[n + 1];
    for (int ii = e0; ii < e1; ++ii) {
        int e = elist[ii];
        int es = srcA[e];
        size_t krow = ((size_t)es * SEQ + l) * 1536 + 512;
        size_t erow = ((size_t)fidx[e] * SEQ + l) * 1024;

        u16x8 ka = *(const u16x8*)&qkv[krow + doff];
        u16x8 kb = *(const u16x8*)&qkv[krow + doff + 8];
        u16x8 ea = *(const u16x8*)&ekv[erow + doff];
        u16x8 eb = *(const u16x8*)&ekv[erow + doff + 8];

        float dot = 0.f;
        #pragma unroll
        for (int i = 0; i < 8; ++i) {
            dot += qi[i]     * (b2f(ka[i]) + b2f(ea[i]));
            dot += qi[i + 8] * (b2f(kb[i]) + b2f(eb[i]));
        }
        dot += __shfl_xor(dot, 1);
        dot += __shfl_xor(dot, 2);
        float alpha = dot * 0.125f;     // 1/sqrt(64)

        float mn = fmaxf(mrun, alpha);
        float f = expf(mrun - mn);      // mrun=-inf -> 0
        float p = expf(alpha - mn);
        s = s * f + p;

        u16x8 va  = *(const u16x8*)&qkv[krow + 512 + doff];
        u16x8 vb  = *(const u16x8*)&qkv[krow + 512 + doff + 8];
        u16x8 eva = *(const u16x8*)&ekv[erow + 512 + doff];
        u16x8 evb = *(const u16x8*)&ekv[erow + 512 + doff + 8];
        #pragma unroll
        for (int i = 0; i < 8; ++i) {
            av[i]     = av[i]     * f + p * (b2f(va[i]) + b2f(eva[i]));
            av[i + 8] = av[i + 8] * f + p * (b2f(vb[i]) + b2f(evb[i]));
        }
        mrun = mn;
    }

    float inv = 1.f / (s + 1e-16f);
    size_t orow = ((size_t)n * SEQ + l) * DIM + doff;
    #pragma unroll
    for (int i = 0; i < 16; ++i) agg[orow + i] = f2b(av[i] * inv);
}

extern "C" void kernel_launch(void* const* d_in, const int* in_sizes, int n_in,
                              void* d_out, int out_size, void* d_ws, size_t ws_size,
                              hipStream_t stream)
{
    const float* hidden = (const float*)d_in[0];
    const int*   eidx   = (const int*)d_in[1];
    const int*   srcA   = eidx;              // edge_index[0]
    const int*   dstA   = eidx + N_EDGES;    // edge_index[1]
    const int*   emap   = (const int*)d_in[2];
    const float* W_qkv  = (const float*)d_in[4];
    const float* W_e    = (const float*)d_in[5];
    const float* W_o    = (const float*)d_in[6];
    const float* xw     = (const float*)d_in[7];
    const float* xew    = (const float*)d_in[8];
    const float* pw     = (const float*)d_in[9];
    const float* W1     = (const float*)d_in[10];
    const float* b1     = (const float*)d_in[11];
    const float* W2     = (const float*)d_in[12];
    const float* b2     = (const float*)d_in[13];

    char* w = (char*)d_ws;
    auto alloc = [&](size_t bytes) { char* p = w; w += (bytes + 255) & ~(size_t)255; return p; };
    u16*  WtQKV  = (u16*)alloc((size_t)NLAYER * 1536 * 512 * 2);
    u16*  WtE    = (u16*)alloc((size_t)NLAYER * 1024 * 512 * 2);
    u16*  WtO    = (u16*)alloc((size_t)NLAYER * 512 * 512 * 2);
    u16*  Wt1    = (u16*)alloc((size_t)NLAYER * 1024 * 512 * 2);
    u16*  Wt2    = (u16*)alloc((size_t)NLAYER * 512 * 1024 * 2);
    float* ssx0  = (float*)alloc((size_t)NROWS_X * 4);
    float* ssx1  = (float*)alloc((size_t)NROWS_X * 4);
    float* ssp0  = (float*)alloc((size_t)NROWS_X * 4);
    float* ssp1  = (float*)alloc((size_t)NROWS_X * 4);
    float* s_f   = (float*)alloc((size_t)NROWS_E * 4);
    int*  cnt    = (int*)alloc((N_NODES + 1) * 4);
    int*  off    = (int*)alloc((N_NODES + 1) * 4);
    int*  cur    = (int*)alloc(N_NODES * 4);
    int*  elist  = (int*)alloc(N_EDGES * 4);
    int*  flag   = (int*)alloc(N_EFEAT * 4);
    int*  newid  = (int*)alloc(N_EFEAT * 4);
    int*  ulist  = (int*)alloc(N_EFEAT * 4);
    int*  fidx   = (int*)alloc(N_EDGES * 4);
    int*  ucnt   = (int*)alloc(256);
    u16*  hb     = (u16*)alloc((size_t)NROWS_X * DIM * 2);
    u16*  ob     = (u16*)alloc((size_t)NROWS_X * DIM * 2);
    u16*  fbf    = (u16*)alloc((size_t)NROWS_E * DIM * 2);
    u16*  qkv    = (u16*)alloc((size_t)NROWS_X * 1536 * 2);
    u16*  aggB   = (u16*)alloc((size_t)NROWS_X * DIM * 2);
    u16*  ffmid  = (u16*)alloc((size_t)NROWS_X * 1024 * 2);
    // ekv scratch lives in d_out's edge region (exact size match: 131072*1024*2B = 16384*4096*4B)
    u16*  ekv    = (u16*)((float*)d_out + (size_t)NROWS_X * DIM);
    float* ssx[2] = { ssx0, ssx1 };
    float* ssp[2] = { ssp0, ssp1 };

    // ---- one-time prep: all transposes + zero-fills (1 dispatch), dedup, CSR, row prep ----
    k_tfall<<<20928, 256, 0, stream>>>(W_qkv, W_e, W_o, W1, W2, xw, xew, pw,
                                       WtQKV, WtE, WtO, Wt1, Wt2, ssx1, ssp0, ssp1, flag);
    k_mark<<<N_EDGES/256, 256, 0, stream>>>(emap, flag);
    k_scanf<<<1, 256, 0, stream>>>(flag, newid, ulist, ucnt);
    k_fidx<<<N_EDGES/256, 256, 0, stream>>>(emap, newid, fidx);
    k_prep<<<NROWS_E/4 + NROWS_X/4, 256, 0, stream>>>(hidden, ulist, ucnt, fbf, s_f, hb, ssx0);
    hipMemsetAsync(cnt, 0, (N_NODES + 1) * 4, stream);
    hipMemsetAsync(cur, 0, N_NODES * 4, stream);
    k_count<<<N_EDGES/256, 256, 0, stream>>>(dstA, cnt);
    k_scan<<<1, 256, 0, stream>>>(cnt, off);
    k_fill<<<N_EDGES/256, 256, 0, stream>>>(dstA, off, cur, elist);

    const int nbQ = (NROWS_X/128)*(1536/128);   // 3072 (div by 8)
    const int nbE = (NROWS_E/128)*(1024/128);   // 8192
    const int nbW = (NROWS_X/128)*(512/128);    // 1024

    // ---- layers (all state bf16; RMS scales from fused sumsq) ----
    for (int l = 0; l < NLAYER; ++l) {
        int last = (l == NLAYER - 1);
        // qkv = rms(h)@Wqkv  +  ekv = rms(feat)@We (dedup'd) — ONE dispatch, tail-filled
        k_gemm2<<<nbQ + nbE, 256, 0, stream>>>(nbQ,
            hb, WtQKV + (size_t)l*1536*512, 1536, 512, 1536/128, nullptr,
            ssx[l], nullptr, 0, nullptr, nullptr, nullptr, qkv,
            fbf, WtE + (size_t)l*1024*512, 1024, 512, 1024/128, ucnt,
            s_f, nullptr, 0, nullptr, nullptr, nullptr, ekv);
        k_attn<<<N_NODES, 256, 0, stream>>>(qkv, ekv, srcA, fidx, off, elist, aggB);
        // out = h + agg@Wo -> ob (bf16) + sumsq -> ssp[l]; last layer also streams the
        // 256 MB edge-region output copy in the same dispatch (overlap).
        if (last) {
            k_gemm_copy<<<nbW + 2048, 256, 0, stream>>>(nbW,
                aggB, WtO + (size_t)l*512*512, 512, 512, 512/128,
                nullptr, nullptr, 0, hb, ssp[l], nullptr, ob,
                (const f32x4v*)(hidden + (size_t)NROWS_X * DIM),
                (f32x4v*)((float*)d_out + (size_t)NROWS_X * DIM));
        } else {
            k_gemm<<<nbW, 256, 0, stream>>>(aggB, WtO + (size_t)l*512*512,
                NROWS_X, 512, 512, 512/128, nullptr,
                nullptr, nullptr, 0, hb, ssp[l], nullptr, ob);
        }
        // ffmid = relu(rms(out)@W1 + b1)   (rowscale from ssp[l])
        k_gemm<<<(NROWS_X/128)*(1024/128), 256, 0, stream>>>(ob, Wt1 + (size_t)l*1024*512,
            NROWS_X, 1024, 512, 1024/128, nullptr,
            ssp[l], b1 + l*1024, 1, nullptr, nullptr, nullptr, ffmid);
        // h' = out + ffmid@W2 + b2  -> hb (bf16) + sumsq -> ssx[l+1]; last: fp32 d_out
        k_gemm<<<(NROWS_X/128)*(512/128), 256, 0, stream>>>(ffmid, Wt2 + (size_t)l*512*1024,
            NROWS_X, 512, 1024, 512/128, nullptr,
            nullptr, b2 + l*512, 0, ob,
            last ? nullptr : ssx[1],
            last ? (float*)d_out : nullptr,
            last ? nullptr : hb);
    }
}

// Round 17
// 1304.700 us; speedup vs baseline: 1.2905x; 1.0116x over previous
//
#include <hip/hip_runtime.h>

typedef unsigned short u16;
typedef unsigned int   u32;
typedef u16   u16x8 __attribute__((ext_vector_type(8)));
typedef __bf16 bf16x8 __attribute__((ext_vector_type(8)));
typedef float f32x4 __attribute__((ext_vector_type(4)));
typedef float f32x4v __attribute__((ext_vector_type(4)));

#define N_NODES 4096
#define N_EDGES 16384
#define N_EFEAT 16384
#define SEQ 8
#define DIM 512
#define NLAYER 2
#define NROWS_X (N_NODES*SEQ)     /* 32768 */
#define NROWS_E (N_EDGES*SEQ)     /* 131072 */

__device__ __forceinline__ float b2f(u16 u){ return __uint_as_float(((u32)u)<<16); }
__device__ __forceinline__ u16 f2b(float f){ u32 b=__float_as_uint(f); b += 0x7FFFu + ((b>>16)&1u); return (u16)(b>>16); }

__device__ __forceinline__ void gl16(const u16* g, u16* l) {
    __builtin_amdgcn_global_load_lds((const __attribute__((address_space(1))) void*)g,
                                     (__attribute__((address_space(3))) void*)l, 16, 0, 0);
}

// ---------------- ALL weight transposes (+norm-w fold) + zero-fills, ONE dispatch ----------------
#define TF_SEG(CNT, SRC, DST, FOLD, KK, NN)                                   \
    if (b < (CNT)) {                                                          \
        int idx = b * 256 + threadIdx.x;                                      \
        int c = idx / (NN), j = idx - c * (NN);                               \
        float v = (SRC)[idx];                                                 \
        if (FOLD) v *= (FOLD)[c];                                             \
        (DST)[(size_t)j * (KK) + c] = f2b(v);                                 \
        return;                                                               \
    }                                                                         \
    b -= (CNT);

__global__ void k_tfall(const float* __restrict__ Wqkv, const float* __restrict__ We,
                        const float* __restrict__ Wo,   const float* __restrict__ W1,
                        const float* __restrict__ W2,
                        const float* __restrict__ xw, const float* __restrict__ xew,
                        const float* __restrict__ pw,
                        u16* __restrict__ WtQKV, u16* __restrict__ WtE, u16* __restrict__ WtO,
                        u16* __restrict__ Wt1, u16* __restrict__ Wt2,
                        float* __restrict__ z0, float* __restrict__ z1,
                        float* __restrict__ z2, int* __restrict__ zf)
{
    int b = blockIdx.x;
    if (b >= 20480) {
        b -= 20480;
        if (b < 128) { z0[b * 256 + threadIdx.x] = 0.f; return; }
        b -= 128;
        if (b < 128) { z1[b * 256 + threadIdx.x] = 0.f; return; }
        b -= 128;
        if (b < 128) { z2[b * 256 + threadIdx.x] = 0.f; return; }
        b -= 128;
        zf[b * 256 + threadIdx.x] = 0; return;
    }
    int l = b / 10240; b -= l * 10240;
    TF_SEG(3072, Wqkv + (size_t)l*512*1536, WtQKV + (size_t)l*1536*512, xw  + l*512, 512, 1536)
    TF_SEG(2048, We   + (size_t)l*512*1024, WtE   + (size_t)l*1024*512, xew + l*512, 512, 1024)
    TF_SEG(1024, Wo   + (size_t)l*512*512,  WtO   + (size_t)l*512*512,  (const float*)nullptr, 512, 512)
    TF_SEG(2048, W1   + (size_t)l*512*1024, Wt1   + (size_t)l*1024*512, pw  + l*512, 512, 1024)
    TF_SEG(2048, W2   + (size_t)l*1024*512, Wt2   + (size_t)l*512*1024, (const float*)nullptr, 1024, 512)
}

// ---------------- merged prep: compact-feature rows (SUMSQ+bf16) + layer-0 node rows ----------
__global__ void k_prep(const float* __restrict__ hidden, const int* __restrict__ ulist,
                       const int* __restrict__ ucnt,
                       u16* __restrict__ fbf, float* __restrict__ s_f,
                       u16* __restrict__ hb, float* __restrict__ ssx0)
{
    int lane = threadIdx.x & 63;
    const float* p;
    u16* dst; float* ssout; int orow;
    if (blockIdx.x < NROWS_E / 4) {
        int fr = blockIdx.x * 4 + (threadIdx.x >> 6);   // compact row = j*8+l
        if (fr >= ucnt[0] * SEQ) return;
        int j = fr >> 3, l = fr & 7;
        p = hidden + ((size_t)(N_NODES + ulist[j]) * SEQ + l) * DIM;
        dst = fbf + (size_t)fr * DIM; ssout = s_f; orow = fr;
    } else {
        int row = (blockIdx.x - NROWS_E / 4) * 4 + (threadIdx.x >> 6);
        p = hidden + (size_t)row * DIM;
        dst = hb + (size_t)row * DIM; ssout = ssx0; orow = row;
    }
    f32x4v v0 = *(const f32x4v*)(p + lane * 8);
    f32x4v v1 = *(const f32x4v*)(p + lane * 8 + 4);
    float ss = v0[0]*v0[0]+v0[1]*v0[1]+v0[2]*v0[2]+v0[3]*v0[3]
             + v1[0]*v1[0]+v1[1]*v1[1]+v1[2]*v1[2]+v1[3]*v1[3];
    #pragma unroll
    for (int d = 1; d < 64; d <<= 1) ss += __shfl_xor(ss, d);
    if (lane == 0) ssout[orow] = ss;
    u16x8 o;
    #pragma unroll
    for (int i = 0; i < 4; ++i) o[i] = f2b(v0[i]);
    #pragma unroll
    for (int i = 0; i < 4; ++i) o[4+i] = f2b(v1[i]);
    *(u16x8*)(dst + lane * 8) = o;
}

// ---------------- dedup mark + CSR count (merged, independent) ----------------
__global__ void k_mc(const int* __restrict__ emap, const int* __restrict__ dstA,
                     int* __restrict__ flag, int* __restrict__ cnt)
{
    int e = blockIdx.x * 256 + threadIdx.x;
    if (e < N_EDGES) { flag[emap[e]] = 1; atomicAdd(&cnt[dstA[e]], 1); }
}
// ---------------- two independent single-block scans (block 0: flag->newid/ulist/ucnt;
// block 1: cnt->off) ----------------
__global__ void k_scans(const int* __restrict__ flag, int* __restrict__ newid,
                        int* __restrict__ ulist, int* __restrict__ ucnt,
                        const int* __restrict__ cnt, int* __restrict__ off)
{
    __shared__ int part[256];
    int t = threadIdx.x;
    if (blockIdx.x == 0) {
        int base = t * 64;
        int loc[64]; int s = 0;
        #pragma unroll
        for (int i = 0; i < 64; ++i) { loc[i] = s; s += flag[base + i]; }
        part[t] = s; __syncthreads();
        for (int d = 1; d < 256; d <<= 1) {
            int v = (t >= d) ? part[t - d] : 0;
            __syncthreads();
            part[t] += v;
            __syncthreads();
        }
        int pre = (t == 0) ? 0 : part[t - 1];
        #pragma unroll
        for (int i = 0; i < 64; ++i) {
            int m = base + i;
            int id = pre + loc[i];
            newid[m] = id;
            if (flag[m]) ulist[id] = m;
        }
        if (t == 255) ucnt[0] = part[255];
    } else {
        int base = t * 16;
        int loc[16]; int s = 0;
        #pragma unroll
        for (int i = 0; i < 16; ++i) { loc[i] = s; s += cnt[base + i]; }
        part[t] = s; __syncthreads();
        for (int d = 1; d < 256; d <<= 1) {
            int v = (t >= d) ? part[t - d] : 0;
            __syncthreads();
            part[t] += v;
            __syncthreads();
        }
        int pre = (t == 0) ? 0 : part[t - 1];
        #pragma unroll
        for (int i = 0; i < 16; ++i) off[base + i] = pre + loc[i];
        if (t == 255) off[N_NODES] = part[255];
    }
}
// ---------------- fidx + CSR fill (merged) ----------------
__global__ void k_ff(const int* __restrict__ emap, const int* __restrict__ newid,
                     int* __restrict__ fidx, const int* __restrict__ dstA,
                     const int* __restrict__ off, int* __restrict__ cur,
                     int* __restrict__ elist)
{
    int e = blockIdx.x * 256 + threadIdx.x;
    if (e < N_EDGES) {
        fidx[e] = newid[emap[e]];
        int d = dstA[e];
        int pos = off[d] + atomicAdd(&cur[d], 1);
        elist[pos] = e;
    }
}

// ---------------- bf16 MFMA GEMM body (proven macro codegen): 2-phase __syncthreads,
// 128x128 tile, BK=32, 4 waves of 64x64, gl_lds w=16 dbuf, interleaved-XCD mapping,
// 0-conflict swizzle, fused epilogue.
#define GEMM_BODY(BID, A_, B_, N_, K_, GX_, MROWS_, SSIN_, BIAS_, RELU_, RESH_, SSOUT_, OUTF_, OUTH_) \
{                                                                                   \
    int tid  = threadIdx.x;                                                         \
    int lane = tid & 63, wid = tid >> 6;                                            \
    int xcd  = (BID) & 7;                                                           \
    int ii_  = (BID) >> 3;                                                          \
    int colt = ii_ % (GX_);                                                         \
    int rowt = (ii_ / (GX_)) * 8 + xcd;                                             \
    int row0 = rowt * 128, col0 = colt * 128;                                       \
    if ((MROWS_) && row0 >= (MROWS_)[0] * SEQ) return;                              \
    int r0 = wid * 32 + (lane >> 2);                                                \
    int r1 = r0 + 16;                                                               \
    int ce0 = ((lane & 3) * 8) ^ (((r0 >> 1) & 3) << 3);                            \
    int ce1 = ((lane & 3) * 8) ^ (((r1 >> 1) & 3) << 3);                            \
    const u16* ga0 = (A_) + (size_t)(row0 + r0) * (K_) + ce0;                       \
    const u16* ga1 = (A_) + (size_t)(row0 + r1) * (K_) + ce1;                       \
    const u16* gb0 = (B_) + (size_t)(col0 + r0) * (K_) + ce0;                       \
    const u16* gb1 = (B_) + (size_t)(col0 + r1) * (K_) + ce1;                       \
    f32x4 acc[4][4];                                                                \
    _Pragma("unroll")                                                               \
    for (int m = 0; m < 4; ++m)                                                     \
        _Pragma("unroll")                                                           \
        for (int n = 0; n < 4; ++n) { f32x4 z = {0.f,0.f,0.f,0.f}; acc[m][n] = z; } \
    int wr = wid >> 1, wc = wid & 1;                                                \
    int m15 = lane & 15, g = lane >> 4;                                             \
    int arow_l = wr * 64 + m15;                                                     \
    int brow_l = wc * 64 + m15;                                                     \
    int ksw = (g * 8) ^ (((m15 >> 1) & 3) << 3);                                    \
    int NT = (K_) / 32;                                                             \
    {                                                                               \
        gl16(ga0, &ldsA[0][wid * 1024]);                                            \
        gl16(ga1, &ldsA[0][wid * 1024 + 512]);                                      \
        gl16(gb0, &ldsB[0][wid * 1024]);                                            \
        gl16(gb1, &ldsB[0][wid * 1024 + 512]);                                      \
    }                                                                               \
    int cur = 0;                                                                    \
    for (int kt = 0; kt < NT; ++kt) {                                               \
        __syncthreads();                                                            \
        if (kt + 1 < NT) {                                                          \
            int ko = (kt + 1) * 32, bf_ = cur ^ 1;                                  \
            gl16(ga0 + ko, &ldsA[bf_][wid * 1024]);                                 \
            gl16(ga1 + ko, &ldsA[bf_][wid * 1024 + 512]);                           \
            gl16(gb0 + ko, &ldsB[bf_][wid * 1024]);                                 \
            gl16(gb1 + ko, &ldsB[bf_][wid * 1024 + 512]);                           \
        }                                                                           \
        bf16x8 af[4], bfr[4];                                                       \
        _Pragma("unroll")                                                           \
        for (int m = 0; m < 4; ++m)                                                 \
            af[m] = *(const bf16x8*)&ldsA[cur][(arow_l + m * 16) * 32 + ksw];       \
        _Pragma("unroll")                                                           \
        for (int n = 0; n < 4; ++n)                                                 \
            bfr[n] = *(const bf16x8*)&ldsB[cur][(brow_l + n * 16) * 32 + ksw];      \
        _Pragma("unroll")                                                           \
        for (int m = 0; m < 4; ++m)                                                 \
            _Pragma("unroll")                                                       \
            for (int n = 0; n < 4; ++n)                                             \
                acc[m][n] = __builtin_amdgcn_mfma_f32_16x16x32_bf16(af[m], bfr[n], acc[m][n], 0, 0, 0); \
        cur ^= 1;                                                                   \
    }                                                                               \
    _Pragma("unroll")                                                               \
    for (int m = 0; m < 4; ++m) {                                                   \
        _Pragma("unroll")                                                           \
        for (int j = 0; j < 4; ++j) {                                               \
            int row = row0 + wr * 64 + m * 16 + g * 4 + j;                          \
            float sc = 0.f;                                                         \
            if (SSIN_) sc = rsqrtf((SSIN_)[row] * (1.f / (float)DIM) + 1e-6f);      \
            float ssa = 0.f;                                                        \
            _Pragma("unroll")                                                       \
            for (int n = 0; n < 4; ++n) {                                           \
                int col = col0 + wc * 64 + n * 16 + m15;                            \
                float v = acc[m][n][j];                                             \
                if (SSIN_) v *= sc;                                                 \
                if (BIAS_) v += (BIAS_)[col];                                       \
                if (RELU_) v = fmaxf(v, 0.f);                                       \
                if (RESH_) v += b2f((RESH_)[(size_t)row * (N_) + col]);             \
                if (OUTF_) (OUTF_)[(size_t)row * (N_) + col] = v;                   \
                if (OUTH_) (OUTH_)[(size_t)row * (N_) + col] = f2b(v);              \
                ssa += v * v;                                                       \
            }                                                                       \
            if (SSOUT_) {                                                           \
                ssa += __shfl_xor(ssa, 1);                                          \
                ssa += __shfl_xor(ssa, 2);                                          \
                ssa += __shfl_xor(ssa, 4);                                          \
                ssa += __shfl_xor(ssa, 8);                                          \
                if (m15 == 0) atomicAdd(&(SSOUT_)[row], ssa);                       \
            }                                                                       \
        }                                                                           \
    }                                                                               \
}

__global__ __launch_bounds__(256, 2) void k_gemm(
    const u16* __restrict__ A, const u16* __restrict__ B,
    int M, int N, int K, int gx, const int* __restrict__ mrows,
    const float* __restrict__ ssin, const float* __restrict__ bias, int relu,
    const u16* __restrict__ resH, float* __restrict__ ssout,
    float* __restrict__ outF, u16* __restrict__ outH)
{
    __shared__ u16 ldsA[2][128 * 32];
    __shared__ u16 ldsB[2][128 * 32];
    GEMM_BODY(blockIdx.x, A, B, N, K, gx, mrows, ssin, bias, relu, resH, ssout, outF, outH)
}

// two independent GEMMs, one dispatch (blocks < nb0 -> set 0; else set 1). nb0 % 8 == 0.
__global__ __launch_bounds__(256, 2) void k_gemm2(
    int nb0,
    const u16* __restrict__ A0, const u16* __restrict__ B0,
    int N0, int K0, int gx0, const int* __restrict__ mrows0,
    const float* __restrict__ ssin0, const float* __restrict__ bias0, int relu0,
    const u16* __restrict__ resH0, float* __restrict__ ssout0,
    float* __restrict__ outF0, u16* __restrict__ outH0,
    const u16* __restrict__ A1, const u16* __restrict__ B1,
    int N1, int K1, int gx1, const int* __restrict__ mrows1,
    const float* __restrict__ ssin1, const float* __restrict__ bias1, int relu1,
    const u16* __restrict__ resH1, float* __restrict__ ssout1,
    float* __restrict__ outF1, u16* __restrict__ outH1)
{
    __shared__ u16 ldsA[2][128 * 32];
    __shared__ u16 ldsB[2][128 * 32];
    if ((int)blockIdx.x < nb0) {
        GEMM_BODY(blockIdx.x, A0, B0, N0, K0, gx0, mrows0, ssin0, bias0, relu0, resH0, ssout0, outF0, outH0)
    } else {
        int bid = blockIdx.x - nb0;
        GEMM_BODY(bid, A1, B1, N1, K1, gx1, mrows1, ssin1, bias1, relu1, resH1, ssout1, outF1, outH1)
    }
}

// GEMM + bulk f32 copy in one dispatch (overlaps the 256 MB edge-region output copy with
// the last-layer Wo GEMM; copy legal — ekv's last reader (attn1) has completed).
__global__ __launch_bounds__(256, 2) void k_gemm_copy(
    int nb0,
    const u16* __restrict__ A, const u16* __restrict__ B,
    int N, int K, int gx,
    const float* __restrict__ ssin, const float* __restrict__ bias, int relu,
    const u16* __restrict__ resH, float* __restrict__ ssout,
    float* __restrict__ outF, u16* __restrict__ outH,
    const f32x4v* __restrict__ csrc, f32x4v* __restrict__ cdst)
{
    __shared__ u16 ldsA[2][128 * 32];
    __shared__ u16 ldsB[2][128 * 32];
    if ((int)blockIdx.x < nb0) {
        GEMM_BODY(blockIdx.x, A, B, N, K, gx, (const int*)nullptr, ssin, bias, relu, resH, ssout, outF, outH)
    } else {
        size_t t = (size_t)(blockIdx.x - nb0) * 256 + threadIdx.x;   // 524288 threads
        #pragma unroll
        for (int k = 0; k < 32; ++k)
            cdst[t + (size_t)k * 524288] = csrc[t + (size_t)k * 524288];
    }
}

// ---------------- per-node attention: online segment softmax + aggregate (RoPE eliminated:
// both sides rotated by the same position l -> orthogonal rotation cancels in the dot).
// Edge features indexed via compact fidx[e] (dedup'd fkv table). ------
__global__ __launch_bounds__(256, 2) void k_attn(
    const u16* __restrict__ qkv, const u16* __restrict__ ekv,
    const int* __restrict__ srcA, const int* __restrict__ fidx,
    const int* __restrict__ off, const int* __restrict__ elist,
    u16* __restrict__ agg)
{
    int n = blockIdx.x;
    int t = threadIdx.x;
    int pair = t >> 2, sub = t & 3;
    int l = pair >> 3, hd = pair & 7;
    int doff = hd * 64 + sub * 16;

    size_t qrow = ((size_t)n * SEQ + l) * 1536;
    float qi[16];
    {
        u16x8 qa = *(const u16x8*)&qkv[qrow + doff];
        u16x8 qb = *(const u16x8*)&qkv[qrow + doff + 8];
        #pragma unroll
        for (int i = 0; i < 8; ++i) { qi[i] = b2f(qa[i]); qi[i + 8] = b2f(qb[i]); }
    }

    float mrun = -INFINITY, s = 0.f;
    float av[16];
    #pragma unroll
    for (int i = 0; i < 16; ++i) av[i] = 0.f;

    int e0 = off[n], e1 = off[n + 1];
    for (int ii = e0; ii < e1; ++ii) {
        int e = elist[ii];
        int es = srcA[e];
        size_t krow = ((size_t)es * SEQ + l) * 1536 + 512;
        size_t erow = ((size_t)fidx[e] * SEQ + l) * 1024;

        u16x8 ka = *(const u16x8*)&qkv[krow + doff];
        u16x8 kb = *(const u16x8*)&qkv[krow + doff + 8];
        u16x8 ea = *(const u16x8*)&ekv[erow + doff];
        u16x8 eb = *(const u16x8*)&ekv[erow + doff + 8];

        float dot = 0.f;
        #pragma unroll
        for (int i = 0; i < 8; ++i) {
            dot += qi[i]     * (b2f(ka[i]) + b2f(ea[i]));
            dot += qi[i + 8] * (b2f(kb[i]) + b2f(eb[i]));
        }
        dot += __shfl_xor(dot, 1);
        dot += __shfl_xor(dot, 2);
        float alpha = dot * 0.125f;     // 1/sqrt(64)

        float mn = fmaxf(mrun, alpha);
        float f = expf(mrun - mn);      // mrun=-inf -> 0
        float p = expf(alpha - mn);
        s = s * f + p;

        u16x8 va  = *(const u16x8*)&qkv[krow + 512 + doff];
        u16x8 vb  = *(const u16x8*)&qkv[krow + 512 + doff + 8];
        u16x8 eva = *(const u16x8*)&ekv[erow + 512 + doff];
        u16x8 evb = *(const u16x8*)&ekv[erow + 512 + doff + 8];
        #pragma unroll
        for (int i = 0; i < 8; ++i) {
            av[i]     = av[i]     * f + p * (b2f(va[i]) + b2f(eva[i]));
            av[i + 8] = av[i + 8] * f + p * (b2f(vb[i]) + b2f(evb[i]));
        }
        mrun = mn;
    }

    float inv = 1.f / (s + 1e-16f);
    size_t orow = ((size_t)n * SEQ + l) * DIM + doff;
    #pragma unroll
    for (int i = 0; i < 16; ++i) agg[orow + i] = f2b(av[i] * inv);
}

extern "C" void kernel_launch(void* const* d_in, const int* in_sizes, int n_in,
                              void* d_out, int out_size, void* d_ws, size_t ws_size,
                              hipStream_t stream)
{
    const float* hidden = (const float*)d_in[0];
    const int*   eidx   = (const int*)d_in[1];
    const int*   srcA   = eidx;              // edge_index[0]
    const int*   dstA   = eidx + N_EDGES;    // edge_index[1]
    const int*   emap   = (const int*)d_in[2];
    const float* W_qkv  = (const float*)d_in[4];
    const float* W_e    = (const float*)d_in[5];
    const float* W_o    = (const float*)d_in[6];
    const float* xw     = (const float*)d_in[7];
    const float* xew    = (const float*)d_in[8];
    const float* pw     = (const float*)d_in[9];
    const float* W1     = (const float*)d_in[10];
    const float* b1     = (const float*)d_in[11];
    const float* W2     = (const float*)d_in[12];
    const float* b2     = (const float*)d_in[13];

    char* w = (char*)d_ws;
    auto alloc = [&](size_t bytes) { char* p = w; w += (bytes + 255) & ~(size_t)255; return p; };
    u16*  WtQKV  = (u16*)alloc((size_t)NLAYER * 1536 * 512 * 2);
    u16*  WtE    = (u16*)alloc((size_t)NLAYER * 1024 * 512 * 2);
    u16*  WtO    = (u16*)alloc((size_t)NLAYER * 512 * 512 * 2);
    u16*  Wt1    = (u16*)alloc((size_t)NLAYER * 1024 * 512 * 2);
    u16*  Wt2    = (u16*)alloc((size_t)NLAYER * 512 * 1024 * 2);
    float* ssx0  = (float*)alloc((size_t)NROWS_X * 4);
    float* ssx1  = (float*)alloc((size_t)NROWS_X * 4);
    float* ssp0  = (float*)alloc((size_t)NROWS_X * 4);
    float* ssp1  = (float*)alloc((size_t)NROWS_X * 4);
    float* s_f   = (float*)alloc((size_t)NROWS_E * 4);
    int*  cnt    = (int*)alloc((N_NODES + 1) * 4);
    int*  off    = (int*)alloc((N_NODES + 1) * 4);
    int*  cur    = (int*)alloc(N_NODES * 4);
    int*  elist  = (int*)alloc(N_EDGES * 4);
    int*  flag   = (int*)alloc(N_EFEAT * 4);
    int*  newid  = (int*)alloc(N_EFEAT * 4);
    int*  ulist  = (int*)alloc(N_EFEAT * 4);
    int*  fidx   = (int*)alloc(N_EDGES * 4);
    int*  ucnt   = (int*)alloc(256);
    u16*  hb     = (u16*)alloc((size_t)NROWS_X * DIM * 2);
    u16*  ob     = (u16*)alloc((size_t)NROWS_X * DIM * 2);
    u16*  fbf    = (u16*)alloc((size_t)NROWS_E * DIM * 2);
    u16*  qkv    = (u16*)alloc((size_t)NROWS_X * 1536 * 2);
    u16*  aggB   = (u16*)alloc((size_t)NROWS_X * DIM * 2);
    u16*  ffmid  = (u16*)alloc((size_t)NROWS_X * 1024 * 2);
    // ekv scratch lives in d_out's edge region (exact size match: 131072*1024*2B = 16384*4096*4B)
    u16*  ekv    = (u16*)((float*)d_out + (size_t)NROWS_X * DIM);

    // ---- one-time prep ----
    k_tfall<<<20928, 256, 0, stream>>>(W_qkv, W_e, W_o, W1, W2, xw, xew, pw,
                                       WtQKV, WtE, WtO, Wt1, Wt2, ssx1, ssp0, ssp1, flag);
    hipMemsetAsync(cnt, 0, (N_NODES + 1) * 4, stream);
    hipMemsetAsync(cur, 0, N_NODES * 4, stream);
    k_mc<<<N_EDGES/256, 256, 0, stream>>>(emap, dstA, flag, cnt);
    k_scans<<<2, 256, 0, stream>>>(flag, newid, ulist, ucnt, cnt, off);
    k_ff<<<N_EDGES/256, 256, 0, stream>>>(emap, newid, fidx, dstA, off, cur, elist);
    k_prep<<<NROWS_E/4 + NROWS_X/4, 256, 0, stream>>>(hidden, ulist, ucnt, fbf, s_f, hb, ssx0);

    const int nbQ = (NROWS_X/128)*(1536/128);   // 3072 (div by 8)
    const int nbE = (NROWS_E/128)*(1024/128);   // 8192
    const int nbW = (NROWS_X/128)*(512/128);    // 1024
    const int nbF1 = (NROWS_X/128)*(1024/128);  // 2048

    // ================= layer 0 =================
    // qkv0 + ekv0 (one dispatch, tail-filled)
    k_gemm2<<<nbQ + nbE, 256, 0, stream>>>(nbQ,
        hb, WtQKV, 1536, 512, 1536/128, nullptr,
        ssx0, nullptr, 0, nullptr, nullptr, nullptr, qkv,
        fbf, WtE, 1024, 512, 1024/128, ucnt,
        s_f, nullptr, 0, nullptr, nullptr, nullptr, ekv);
    k_attn<<<N_NODES, 256, 0, stream>>>(qkv, ekv, srcA, fidx, off, elist, aggB);
    // out0 = h + agg@Wo -> ob + sumsq -> ssp0
    k_gemm<<<nbW, 256, 0, stream>>>(aggB, WtO, NROWS_X, 512, 512, 512/128, nullptr,
        nullptr, nullptr, 0, hb, ssp0, nullptr, ob);
    // ffmid0 = relu(rms(out0)@W1 + b1)
    k_gemm<<<nbF1, 256, 0, stream>>>(ob, Wt1, NROWS_X, 1024, 512, 1024/128, nullptr,
        ssp0, b1, 1, nullptr, nullptr, nullptr, ffmid);
    // h1 = out0 + ffmid0@W2 + b2 -> hb + sumsq -> ssx1  MERGED WITH  ekv1 = rms(feat)@We[1]
    // (ekv1 independent of FF2; its prior reader attn0 has completed; fills FF2's tail)
    k_gemm2<<<nbW + nbE, 256, 0, stream>>>(nbW,
        ffmid, Wt2, 512, 1024, 512/128, nullptr,
        nullptr, b2, 0, ob, ssx1, nullptr, hb,
        fbf, WtE + (size_t)1024*512, 1024, 512, 1024/128, ucnt,
        s_f, nullptr, 0, nullptr, nullptr, nullptr, ekv);

    // ================= layer 1 =================
    // qkv1 (alone — ekv1 already done)
    k_gemm<<<nbQ, 256, 0, stream>>>(hb, WtQKV + (size_t)1536*512,
        NROWS_X, 1536, 512, 1536/128, nullptr,
        ssx1, nullptr, 0, nullptr, nullptr, nullptr, qkv);
    k_attn<<<N_NODES, 256, 0, stream>>>(qkv, ekv, srcA, fidx, off, elist, aggB);
    // out1 = h1 + agg@Wo[1] -> ob + sumsq -> ssp1 ; + 256 MB edge-region copy (overlap)
    k_gemm_copy<<<nbW + 2048, 256, 0, stream>>>(nbW,
        aggB, WtO + (size_t)512*512, 512, 512, 512/128,
        nullptr, nullptr, 0, hb, ssp1, nullptr, ob,
        (const f32x4v*)(hidden + (size_t)NROWS_X * DIM),
        (f32x4v*)((float*)d_out + (size_t)NROWS_X * DIM));
    // ffmid1 = relu(rms(out1)@W1[1] + b1[1])
    k_gemm<<<nbF1, 256, 0, stream>>>(ob, Wt1 + (size_t)1024*512,
        NROWS_X, 1024, 512, 1024/128, nullptr,
        ssp1, b1 + 1024, 1, nullptr, nullptr, nullptr, ffmid);
    // out = out1 + ffmid1@W2[1] + b2[1] -> fp32 d_out (node region)
    k_gemm<<<nbW, 256, 0, stream>>>(ffmid, Wt2 + (size_t)512*1024,
        NROWS_X, 512, 1024, 512/128, nullptr,
        nullptr, b2 + 512, 0, ob, nullptr, (float*)d_out, nullptr);
}

// Round 18
// 1303.049 us; speedup vs baseline: 1.2922x; 1.0013x over previous
//
#include <hip/hip_runtime.h>

typedef unsigned short u16;
typedef unsigned int   u32;
typedef u16   u16x8 __attribute__((ext_vector_type(8)));
typedef __bf16 bf16x8 __attribute__((ext_vector_type(8)));
typedef float f32x4 __attribute__((ext_vector_type(4)));
typedef float f32x4v __attribute__((ext_vector_type(4)));

#define N_NODES 4096
#define N_EDGES 16384
#define N_EFEAT 16384
#define SEQ 8
#define DIM 512
#define NLAYER 2
#define NROWS_X (N_NODES*SEQ)     /* 32768 */
#define NROWS_E (N_EDGES*SEQ)     /* 131072 */

__device__ __forceinline__ float b2f(u16 u){ return __uint_as_float(((u32)u)<<16); }
__device__ __forceinline__ u16 f2b(float f){ u32 b=__float_as_uint(f); b += 0x7FFFu + ((b>>16)&1u); return (u16)(b>>16); }

__device__ __forceinline__ void gl16(const u16* g, u16* l) {
    __builtin_amdgcn_global_load_lds((const __attribute__((address_space(1))) void*)g,
                                     (__attribute__((address_space(3))) void*)l, 16, 0, 0);
}

// ---------------- ALL weight transposes (+norm-w fold) + ALL zero-fills, ONE dispatch ----------
// 20480 tf blocks + ssx1 128 + ssp0 128 + ssp1 128 + flag 64 + cnt 17 + cur 16 = 20961
#define TF_SEG(CNT, SRC, DST, FOLD, KK, NN)                                   \
    if (b < (CNT)) {                                                          \
        int idx = b * 256 + threadIdx.x;                                      \
        int c = idx / (NN), j = idx - c * (NN);                               \
        float v = (SRC)[idx];                                                 \
        if (FOLD) v *= (FOLD)[c];                                             \
        (DST)[(size_t)j * (KK) + c] = f2b(v);                                 \
        return;                                                               \
    }                                                                         \
    b -= (CNT);

__global__ void k_tfall(const float* __restrict__ Wqkv, const float* __restrict__ We,
                        const float* __restrict__ Wo,   const float* __restrict__ W1,
                        const float* __restrict__ W2,
                        const float* __restrict__ xw, const float* __restrict__ xew,
                        const float* __restrict__ pw,
                        u16* __restrict__ WtQKV, u16* __restrict__ WtE, u16* __restrict__ WtO,
                        u16* __restrict__ Wt1, u16* __restrict__ Wt2,
                        float* __restrict__ z0, float* __restrict__ z1,
                        float* __restrict__ z2, int* __restrict__ zf,
                        int* __restrict__ zcnt, int* __restrict__ zcur)
{
    int b = blockIdx.x;
    if (b >= 20480) {
        b -= 20480;
        if (b < 128) { z0[b * 256 + threadIdx.x] = 0.f; return; }
        b -= 128;
        if (b < 128) { z1[b * 256 + threadIdx.x] = 0.f; return; }
        b -= 128;
        if (b < 128) { z2[b * 256 + threadIdx.x] = 0.f; return; }
        b -= 128;
        if (b < 64)  { zf[b * 256 + threadIdx.x] = 0; return; }
        b -= 64;
        if (b < 17)  { int i = b * 256 + threadIdx.x; if (i <= N_NODES) zcnt[i] = 0; return; }
        b -= 17;
        { int i = b * 256 + threadIdx.x; if (i < N_NODES) zcur[i] = 0; return; }
    }
    int l = b / 10240; b -= l * 10240;
    TF_SEG(3072, Wqkv + (size_t)l*512*1536, WtQKV + (size_t)l*1536*512, xw  + l*512, 512, 1536)
    TF_SEG(2048, We   + (size_t)l*512*1024, WtE   + (size_t)l*1024*512, xew + l*512, 512, 1024)
    TF_SEG(1024, Wo   + (size_t)l*512*512,  WtO   + (size_t)l*512*512,  (const float*)nullptr, 512, 512)
    TF_SEG(2048, W1   + (size_t)l*512*1024, Wt1   + (size_t)l*1024*512, pw  + l*512, 512, 1024)
    TF_SEG(2048, W2   + (size_t)l*1024*512, Wt2   + (size_t)l*512*1024, (const float*)nullptr, 1024, 512)
}

// ---------------- dedup mark + CSR count (merged, independent) ----------------
__global__ void k_mc(const int* __restrict__ emap, const int* __restrict__ dstA,
                     int* __restrict__ flag, int* __restrict__ cnt)
{
    int e = blockIdx.x * 256 + threadIdx.x;
    if (e < N_EDGES) { flag[emap[e]] = 1; atomicAdd(&cnt[dstA[e]], 1); }
}
// ---------------- two independent single-block scans ----------------
__global__ void k_scans(const int* __restrict__ flag, int* __restrict__ newid,
                        int* __restrict__ ulist, int* __restrict__ ucnt,
                        const int* __restrict__ cnt, int* __restrict__ off)
{
    __shared__ int part[256];
    int t = threadIdx.x;
    if (blockIdx.x == 0) {
        int base = t * 64;
        int loc[64]; int s = 0;
        #pragma unroll
        for (int i = 0; i < 64; ++i) { loc[i] = s; s += flag[base + i]; }
        part[t] = s; __syncthreads();
        for (int d = 1; d < 256; d <<= 1) {
            int v = (t >= d) ? part[t - d] : 0;
            __syncthreads();
            part[t] += v;
            __syncthreads();
        }
        int pre = (t == 0) ? 0 : part[t - 1];
        #pragma unroll
        for (int i = 0; i < 64; ++i) {
            int m = base + i;
            int id = pre + loc[i];
            newid[m] = id;
            if (flag[m]) ulist[id] = m;
        }
        if (t == 255) ucnt[0] = part[255];
    } else {
        int base = t * 16;
        int loc[16]; int s = 0;
        #pragma unroll
        for (int i = 0; i < 16; ++i) { loc[i] = s; s += cnt[base + i]; }
        part[t] = s; __syncthreads();
        for (int d = 1; d < 256; d <<= 1) {
            int v = (t >= d) ? part[t - d] : 0;
            __syncthreads();
            part[t] += v;
            __syncthreads();
        }
        int pre = (t == 0) ? 0 : part[t - 1];
        #pragma unroll
        for (int i = 0; i < 16; ++i) off[base + i] = pre + loc[i];
        if (t == 255) off[N_NODES] = part[255];
    }
}
// ---------------- fidx + CSR fill + row prep (all depend only on k_scans) ----------------
// blocks [0,64): fidx+fill ; [64, 64+NROWS_E/4): feature rows ; rest: node rows
__global__ void k_ffprep(const int* __restrict__ emap, const int* __restrict__ newid,
                         int* __restrict__ fidx, const int* __restrict__ dstA,
                         const int* __restrict__ off, int* __restrict__ cur,
                         int* __restrict__ elist,
                         const float* __restrict__ hidden, const int* __restrict__ ulist,
                         const int* __restrict__ ucnt,
                         u16* __restrict__ fbf, float* __restrict__ s_f,
                         u16* __restrict__ hb, float* __restrict__ ssx0)
{
    if (blockIdx.x < 64) {
        int e = blockIdx.x * 256 + threadIdx.x;
        fidx[e] = newid[emap[e]];
        int d = dstA[e];
        int pos = off[d] + atomicAdd(&cur[d], 1);
        elist[pos] = e;
        return;
    }
    int lane = threadIdx.x & 63;
    const float* p;
    u16* dst; float* ssout; int orow;
    int bb = blockIdx.x - 64;
    if (bb < NROWS_E / 4) {
        int fr = bb * 4 + (threadIdx.x >> 6);
        if (fr >= ucnt[0] * SEQ) return;
        int j = fr >> 3, l = fr & 7;
        p = hidden + ((size_t)(N_NODES + ulist[j]) * SEQ + l) * DIM;
        dst = fbf + (size_t)fr * DIM; ssout = s_f; orow = fr;
    } else {
        int row = (bb - NROWS_E / 4) * 4 + (threadIdx.x >> 6);
        p = hidden + (size_t)row * DIM;
        dst = hb + (size_t)row * DIM; ssout = ssx0; orow = row;
    }
    f32x4v v0 = *(const f32x4v*)(p + lane * 8);
    f32x4v v1 = *(const f32x4v*)(p + lane * 8 + 4);
    float ss = v0[0]*v0[0]+v0[1]*v0[1]+v0[2]*v0[2]+v0[3]*v0[3]
             + v1[0]*v1[0]+v1[1]*v1[1]+v1[2]*v1[2]+v1[3]*v1[3];
    #pragma unroll
    for (int d = 1; d < 64; d <<= 1) ss += __shfl_xor(ss, d);
    if (lane == 0) ssout[orow] = ss;
    u16x8 o;
    #pragma unroll
    for (int i = 0; i < 4; ++i) o[i] = f2b(v0[i]);
    #pragma unroll
    for (int i = 0; i < 4; ++i) o[4+i] = f2b(v1[i]);
    *(u16x8*)(dst + lane * 8) = o;
}

// ---------------- bf16 MFMA GEMM body (proven macro codegen): 2-phase __syncthreads,
// 128x128 tile, BK=32, 4 waves of 64x64, gl_lds w=16 dbuf, interleaved-XCD mapping,
// 0-conflict swizzle, fused epilogue.
#define GEMM_BODY(BID, A_, B_, N_, K_, GX_, MROWS_, SSIN_, BIAS_, RELU_, RESH_, SSOUT_, OUTF_, OUTH_) \
{                                                                                   \
    int tid  = threadIdx.x;                                                         \
    int lane = tid & 63, wid = tid >> 6;                                            \
    int xcd  = (BID) & 7;                                                           \
    int ii_  = (BID) >> 3;                                                          \
    int colt = ii_ % (GX_);                                                         \
    int rowt = (ii_ / (GX_)) * 8 + xcd;                                             \
    int row0 = rowt * 128, col0 = colt * 128;                                       \
    if ((MROWS_) && row0 >= (MROWS_)[0] * SEQ) return;                              \
    int r0 = wid * 32 + (lane >> 2);                                                \
    int r1 = r0 + 16;                                                               \
    int ce0 = ((lane & 3) * 8) ^ (((r0 >> 1) & 3) << 3);                            \
    int ce1 = ((lane & 3) * 8) ^ (((r1 >> 1) & 3) << 3);                            \
    const u16* ga0 = (A_) + (size_t)(row0 + r0) * (K_) + ce0;                       \
    const u16* ga1 = (A_) + (size_t)(row0 + r1) * (K_) + ce1;                       \
    const u16* gb0 = (B_) + (size_t)(col0 + r0) * (K_) + ce0;                       \
    const u16* gb1 = (B_) + (size_t)(col0 + r1) * (K_) + ce1;                       \
    f32x4 acc[4][4];                                                                \
    _Pragma("unroll")                                                               \
    for (int m = 0; m < 4; ++m)                                                     \
        _Pragma("unroll")                                                           \
        for (int n = 0; n < 4; ++n) { f32x4 z = {0.f,0.f,0.f,0.f}; acc[m][n] = z; } \
    int wr = wid >> 1, wc = wid & 1;                                                \
    int m15 = lane & 15, g = lane >> 4;                                             \
    int arow_l = wr * 64 + m15;                                                     \
    int brow_l = wc * 64 + m15;                                                     \
    int ksw = (g * 8) ^ (((m15 >> 1) & 3) << 3);                                    \
    int NT = (K_) / 32;                                                             \
    {                                                                               \
        gl16(ga0, &ldsA[0][wid * 1024]);                                            \
        gl16(ga1, &ldsA[0][wid * 1024 + 512]);                                      \
        gl16(gb0, &ldsB[0][wid * 1024]);                                            \
        gl16(gb1, &ldsB[0][wid * 1024 + 512]);                                      \
    }                                                                               \
    int cur = 0;                                                                    \
    for (int kt = 0; kt < NT; ++kt) {                                               \
        __syncthreads();                                                            \
        if (kt + 1 < NT) {                                                          \
            int ko = (kt + 1) * 32, bf_ = cur ^ 1;                                  \
            gl16(ga0 + ko, &ldsA[bf_][wid * 1024]);                                 \
            gl16(ga1 + ko, &ldsA[bf_][wid * 1024 + 512]);                           \
            gl16(gb0 + ko, &ldsB[bf_][wid * 1024]);                                 \
            gl16(gb1 + ko, &ldsB[bf_][wid * 1024 + 512]);                           \
        }                                                                           \
        bf16x8 af[4], bfr[4];                                                       \
        _Pragma("unroll")                                                           \
        for (int m = 0; m < 4; ++m)                                                 \
            af[m] = *(const bf16x8*)&ldsA[cur][(arow_l + m * 16) * 32 + ksw];       \
        _Pragma("unroll")                                                           \
        for (int n = 0; n < 4; ++n)                                                 \
            bfr[n] = *(const bf16x8*)&ldsB[cur][(brow_l + n * 16) * 32 + ksw];      \
        _Pragma("unroll")                                                           \
        for (int m = 0; m < 4; ++m)                                                 \
            _Pragma("unroll")                                                       \
            for (int n = 0; n < 4; ++n)                                             \
                acc[m][n] = __builtin_amdgcn_mfma_f32_16x16x32_bf16(af[m], bfr[n], acc[m][n], 0, 0, 0); \
        cur ^= 1;                                                                   \
    }                                                                               \
    _Pragma("unroll")                                                               \
    for (int m = 0; m < 4; ++m) {                                                   \
        _Pragma("unroll")                                                           \
        for (int j = 0; j < 4; ++j) {                                               \
            int row = row0 + wr * 64 + m * 16 + g * 4 + j;                          \
            float sc = 0.f;                                                         \
            if (SSIN_) sc = rsqrtf((SSIN_)[row] * (1.f / (float)DIM) + 1e-6f);      \
            float ssa = 0.f;                                                        \
            _Pragma("unroll")                                                       \
            for (int n = 0; n < 4; ++n) {                                           \
                int col = col0 + wc * 64 + n * 16 + m15;                            \
                float v = acc[m][n][j];                                             \
                if (SSIN_) v *= sc;                                                 \
                if (BIAS_) v += (BIAS_)[col];                                       \
                if (RELU_) v = fmaxf(v, 0.f);                                       \
                if (RESH_) v += b2f((RESH_)[(size_t)row * (N_) + col]);             \
                if (OUTF_) (OUTF_)[(size_t)row * (N_) + col] = v;                   \
                if (OUTH_) (OUTH_)[(size_t)row * (N_) + col] = f2b(v);              \
                ssa += v * v;                                                       \
            }                                                                       \
            if (SSOUT_) {                                                           \
                ssa += __shfl_xor(ssa, 1);                                          \
                ssa += __shfl_xor(ssa, 2);                                          \
                ssa += __shfl_xor(ssa, 4);                                          \
                ssa += __shfl_xor(ssa, 8);                                          \
                if (m15 == 0) atomicAdd(&(SSOUT_)[row], ssa);                       \
            }                                                                       \
        }                                                                           \
    }                                                                               \
}

__global__ __launch_bounds__(256, 2) void k_gemm(
    const u16* __restrict__ A, const u16* __restrict__ B,
    int M, int N, int K, int gx, const int* __restrict__ mrows,
    const float* __restrict__ ssin, const float* __restrict__ bias, int relu,
    const u16* __restrict__ resH, float* __restrict__ ssout,
    float* __restrict__ outF, u16* __restrict__ outH)
{
    __shared__ u16 ldsA[2][128 * 32];
    __shared__ u16 ldsB[2][128 * 32];
    GEMM_BODY(blockIdx.x, A, B, N, K, gx, mrows, ssin, bias, relu, resH, ssout, outF, outH)
}

// two independent GEMMs, one dispatch (blocks < nb0 -> set 0; else set 1). nb0 % 8 == 0.
__global__ __launch_bounds__(256, 2) void k_gemm2(
    int nb0,
    const u16* __restrict__ A0, const u16* __restrict__ B0,
    int N0, int K0, int gx0, const int* __restrict__ mrows0,
    const float* __restrict__ ssin0, const float* __restrict__ bias0, int relu0,
    const u16* __restrict__ resH0, float* __restrict__ ssout0,
    float* __restrict__ outF0, u16* __restrict__ outH0,
    const u16* __restrict__ A1, const u16* __restrict__ B1,
    int N1, int K1, int gx1, const int* __restrict__ mrows1,
    const float* __restrict__ ssin1, const float* __restrict__ bias1, int relu1,
    const u16* __restrict__ resH1, float* __restrict__ ssout1,
    float* __restrict__ outF1, u16* __restrict__ outH1)
{
    __shared__ u16 ldsA[2][128 * 32];
    __shared__ u16 ldsB[2][128 * 32];
    if ((int)blockIdx.x < nb0) {
        GEMM_BODY(blockIdx.x, A0, B0, N0, K0, gx0, mrows0, ssin0, bias0, relu0, resH0, ssout0, outF0, outH0)
    } else {
        int bid = blockIdx.x - nb0;
        GEMM_BODY(bid, A1, B1, N1, K1, gx1, mrows1, ssin1, bias1, relu1, resH1, ssout1, outF1, outH1)
    }
}

// GEMM + a SLICE of the 256 MB edge-region copy (copy block ids [coff, coff+grid-nb0);
// slice t handles float4s t + k*524288, k<32; 2048 copy blocks total across dispatches).
__global__ __launch_bounds__(256, 2) void k_gemm_copy(
    int nb0, int coff,
    const u16* __restrict__ A, const u16* __restrict__ B,
    int N, int K, int gx,
    const float* __restrict__ ssin, const float* __restrict__ bias, int relu,
    const u16* __restrict__ resH, float* __restrict__ ssout,
    float* __restrict__ outF, u16* __restrict__ outH,
    const f32x4v* __restrict__ csrc, f32x4v* __restrict__ cdst)
{
    __shared__ u16 ldsA[2][128 * 32];
    __shared__ u16 ldsB[2][128 * 32];
    if ((int)blockIdx.x < nb0) {
        GEMM_BODY(blockIdx.x, A, B, N, K, gx, (const int*)nullptr, ssin, bias, relu, resH, ssout, outF, outH)
    } else {
        size_t t = (size_t)(blockIdx.x - nb0 + coff) * 256 + threadIdx.x;
        #pragma unroll
        for (int k = 0; k < 32; ++k)
            cdst[t + (size_t)k * 524288] = csrc[t + (size_t)k * 524288];
    }
}

// ---------------- per-node attention (RoPE eliminated; dedup'd edge features) ----------------
__global__ __launch_bounds__(256, 2) void k_attn(
    const u16* __restrict__ qkv, const u16* __restrict__ ekv,
    const int* __restrict__ srcA, const int* __restrict__ fidx,
    const int* __restrict__ off, const int* __restrict__ elist,
    u16* __restrict__ agg)
{
    int n = blockIdx.x;
    int t = threadIdx.x;
    int pair = t >> 2, sub = t & 3;
    int l = pair >> 3, hd = pair & 7;
    int doff = hd * 64 + sub * 16;

    size_t qrow = ((size_t)n * SEQ + l) * 1536;
    float qi[16];
    {
        u16x8 qa = *(const u16x8*)&qkv[qrow + doff];
        u16x8 qb = *(const u16x8*)&qkv[qrow + doff + 8];
        #pragma unroll
        for (int i = 0; i < 8; ++i) { qi[i] = b2f(qa[i]); qi[i + 8] = b2f(qb[i]); }
    }

    float mrun = -INFINITY, s = 0.f;
    float av[16];
    #pragma unroll
    for (int i = 0; i < 16; ++i) av[i] = 0.f;

    int e0 = off[n], e1 = off[n + 1];
    for (int ii = e0; ii < e1; ++ii) {
        int e = elist[ii];
        int es = srcA[e];
        size_t krow = ((size_t)es * SEQ + l) * 1536 + 512;
        size_t erow = ((size_t)fidx[e] * SEQ + l) * 1024;

        u16x8 ka = *(const u16x8*)&qkv[krow + doff];
        u16x8 kb = *(const u16x8*)&qkv[krow + doff + 8];
        u16x8 ea = *(const u16x8*)&ekv[erow + doff];
        u16x8 eb = *(const u16x8*)&ekv[erow + doff + 8];

        float dot = 0.f;
        #pragma unroll
        for (int i = 0; i < 8; ++i) {
            dot += qi[i]     * (b2f(ka[i]) + b2f(ea[i]));
            dot += qi[i + 8] * (b2f(kb[i]) + b2f(eb[i]));
        }
        dot += __shfl_xor(dot, 1);
        dot += __shfl_xor(dot, 2);
        float alpha = dot * 0.125f;     // 1/sqrt(64)

        float mn = fmaxf(mrun, alpha);
        float f = expf(mrun - mn);      // mrun=-inf -> 0
        float p = expf(alpha - mn);
        s = s * f + p;

        u16x8 va  = *(const u16x8*)&qkv[krow + 512 + doff];
        u16x8 vb  = *(const u16x8*)&qkv[krow + 512 + doff + 8];
        u16x8 eva = *(const u16x8*)&ekv[erow + 512 + doff];
        u16x8 evb = *(const u16x8*)&ekv[erow + 512 + doff + 8];
        #pragma unroll
        for (int i = 0; i < 8; ++i) {
            av[i]     = av[i]     * f + p * (b2f(va[i]) + b2f(eva[i]));
            av[i + 8] = av[i + 8] * f + p * (b2f(vb[i]) + b2f(evb[i]));
        }
        mrun = mn;
    }

    float inv = 1.f / (s + 1e-16f);
    size_t orow = ((size_t)n * SEQ + l) * DIM + doff;
    #pragma unroll
    for (int i = 0; i < 16; ++i) agg[orow + i] = f2b(av[i] * inv);
}

extern "C" void kernel_launch(void* const* d_in, const int* in_sizes, int n_in,
                              void* d_out, int out_size, void* d_ws, size_t ws_size,
                              hipStream_t stream)
{
    const float* hidden = (const float*)d_in[0];
    const int*   eidx   = (const int*)d_in[1];
    const int*   srcA   = eidx;              // edge_index[0]
    const int*   dstA   = eidx + N_EDGES;    // edge_index[1]
    const int*   emap   = (const int*)d_in[2];
    const float* W_qkv  = (const float*)d_in[4];
    const float* W_e    = (const float*)d_in[5];
    const float* W_o    = (const float*)d_in[6];
    const float* xw     = (const float*)d_in[7];
    const float* xew    = (const float*)d_in[8];
    const float* pw     = (const float*)d_in[9];
    const float* W1     = (const float*)d_in[10];
    const float* b1     = (const float*)d_in[11];
    const float* W2     = (const float*)d_in[12];
    const float* b2     = (const float*)d_in[13];

    char* w = (char*)d_ws;
    auto alloc = [&](size_t bytes) { char* p = w; w += (bytes + 255) & ~(size_t)255; return p; };
    u16*  WtQKV  = (u16*)alloc((size_t)NLAYER * 1536 * 512 * 2);
    u16*  WtE    = (u16*)alloc((size_t)NLAYER * 1024 * 512 * 2);
    u16*  WtO    = (u16*)alloc((size_t)NLAYER * 512 * 512 * 2);
    u16*  Wt1    = (u16*)alloc((size_t)NLAYER * 1024 * 512 * 2);
    u16*  Wt2    = (u16*)alloc((size_t)NLAYER * 512 * 1024 * 2);
    float* ssx0  = (float*)alloc((size_t)NROWS_X * 4);
    float* ssx1  = (float*)alloc((size_t)NROWS_X * 4);
    float* ssp0  = (float*)alloc((size_t)NROWS_X * 4);
    float* ssp1  = (float*)alloc((size_t)NROWS_X * 4);
    float* s_f   = (float*)alloc((size_t)NROWS_E * 4);
    int*  cnt    = (int*)alloc((N_NODES + 1) * 4);
    int*  off    = (int*)alloc((N_NODES + 1) * 4);
    int*  cur    = (int*)alloc(N_NODES * 4);
    int*  elist  = (int*)alloc(N_EDGES * 4);
    int*  flag   = (int*)alloc(N_EFEAT * 4);
    int*  newid  = (int*)alloc(N_EFEAT * 4);
    int*  ulist  = (int*)alloc(N_EFEAT * 4);
    int*  fidx   = (int*)alloc(N_EDGES * 4);
    int*  ucnt   = (int*)alloc(256);
    u16*  hb     = (u16*)alloc((size_t)NROWS_X * DIM * 2);
    u16*  ob     = (u16*)alloc((size_t)NROWS_X * DIM * 2);
    u16*  fbf    = (u16*)alloc((size_t)NROWS_E * DIM * 2);
    u16*  qkv    = (u16*)alloc((size_t)NROWS_X * 1536 * 2);
    u16*  aggB   = (u16*)alloc((size_t)NROWS_X * DIM * 2);
    u16*  ffmid  = (u16*)alloc((size_t)NROWS_X * 1024 * 2);
    // ekv scratch lives in d_out's edge region (exact size match: 131072*1024*2B = 16384*4096*4B)
    u16*  ekv    = (u16*)((float*)d_out + (size_t)NROWS_X * DIM);

    // ---- one-time prep: 4 dispatches ----
    k_tfall<<<20961, 256, 0, stream>>>(W_qkv, W_e, W_o, W1, W2, xw, xew, pw,
                                       WtQKV, WtE, WtO, Wt1, Wt2, ssx1, ssp0, ssp1,
                                       flag, cnt, cur);
    k_mc<<<N_EDGES/256, 256, 0, stream>>>(emap, dstA, flag, cnt);
    k_scans<<<2, 256, 0, stream>>>(flag, newid, ulist, ucnt, cnt, off);
    k_ffprep<<<64 + NROWS_E/4 + NROWS_X/4, 256, 0, stream>>>(emap, newid, fidx, dstA, off, cur,
        elist, hidden, ulist, ucnt, fbf, s_f, hb, ssx0);

    const int nbQ = (NROWS_X/128)*(1536/128);   // 3072 (div by 8)
    const int nbE = (NROWS_E/128)*(1024/128);   // 8192
    const int nbW = (NROWS_X/128)*(512/128);    // 1024
    const int nbF1 = (NROWS_X/128)*(1024/128);  // 2048
    const f32x4v* csrc = (const f32x4v*)(hidden + (size_t)NROWS_X * DIM);
    f32x4v*       cdst = (f32x4v*)((float*)d_out + (size_t)NROWS_X * DIM);

    // ================= layer 0 =================
    k_gemm2<<<nbQ + nbE, 256, 0, stream>>>(nbQ,
        hb, WtQKV, 1536, 512, 1536/128, nullptr,
        ssx0, nullptr, 0, nullptr, nullptr, nullptr, qkv,
        fbf, WtE, 1024, 512, 1024/128, ucnt,
        s_f, nullptr, 0, nullptr, nullptr, nullptr, ekv);
    k_attn<<<N_NODES, 256, 0, stream>>>(qkv, ekv, srcA, fidx, off, elist, aggB);
    k_gemm<<<nbW, 256, 0, stream>>>(aggB, WtO, NROWS_X, 512, 512, 512/128, nullptr,
        nullptr, nullptr, 0, hb, ssp0, nullptr, ob);
    k_gemm<<<nbF1, 256, 0, stream>>>(ob, Wt1, NROWS_X, 1024, 512, 1024/128, nullptr,
        ssp0, b1, 1, nullptr, nullptr, nullptr, ffmid);
    // FF2_0 merged with ekv1 (independent; fills tail)
    k_gemm2<<<nbW + nbE, 256, 0, stream>>>(nbW,
        ffmid, Wt2, 512, 1024, 512/128, nullptr,
        nullptr, b2, 0, ob, ssx1, nullptr, hb,
        fbf, WtE + (size_t)1024*512, 1024, 512, 1024/128, ucnt,
        s_f, nullptr, 0, nullptr, nullptr, nullptr, ekv);

    // ================= layer 1 =================
    k_gemm<<<nbQ, 256, 0, stream>>>(hb, WtQKV + (size_t)1536*512,
        NROWS_X, 1536, 512, 1536/128, nullptr,
        ssx1, nullptr, 0, nullptr, nullptr, nullptr, qkv);
    k_attn<<<N_NODES, 256, 0, stream>>>(qkv, ekv, srcA, fidx, off, elist, aggB);
    // edge-region copy spread across Wo1 / FF1_1 / FF2_1 (legal: attn1 was ekv's last reader)
    k_gemm_copy<<<nbW + 683, 256, 0, stream>>>(nbW, 0,
        aggB, WtO + (size_t)512*512, 512, 512, 512/128,
        nullptr, nullptr, 0, hb, ssp1, nullptr, ob, csrc, cdst);
    k_gemm_copy<<<nbF1 + 683, 256, 0, stream>>>(nbF1, 683,
        ob, Wt1 + (size_t)1024*512, 1024, 512, 1024/128,
        ssp1, b1 + 1024, 1, nullptr, nullptr, nullptr, ffmid, csrc, cdst);
    k_gemm_copy<<<nbW + 682, 256, 0, stream>>>(nbW, 1366,
        ffmid, Wt2 + (size_t)512*1024, 512, 1024, 512/128,
        nullptr, b2 + 512, 0, ob, nullptr, (float*)d_out, nullptr, csrc, cdst);
}